// Round 6
// baseline (1183.791 us; speedup 1.0000x reference)
//
#include <hip/hip_runtime.h>
#include <cstdint>
#include <cstddef>

#define NDOM   32768
#define DIN    128
#define DMODEL 256
#define NHEAD  4
#define NLAYER 4
#define DFFN   1024
#define BATCH  64
#define SEQ    672
#define DHEAD  64
#define MROWS  (BATCH*SEQ)   // 43008

typedef unsigned short u16;
typedef __attribute__((ext_vector_type(8))) short bf8;   // 8 bf16 (4 VGPRs)
typedef __attribute__((ext_vector_type(4))) float f4;    // MFMA accumulator

__device__ inline u16 f2b(float x) {            // f32 -> bf16 RNE
    union { float f; unsigned u; } c; c.f = x;
    unsigned r = c.u + 0x7fffu + ((c.u >> 16) & 1u);
    return (u16)(r >> 16);
}

__device__ inline void gload16(const void* g, const void* l) {
    __builtin_amdgcn_global_load_lds(
        (const __attribute__((address_space(1))) void*)g,
        (__attribute__((address_space(3))) void*)l, 16, 0, 0);
}

// ---------------- setup ----------------

__global__ void k_zero_counts(int* __restrict__ counts) {
    if (threadIdx.x < BATCH) counts[threadIdx.x] = 0;
}

__global__ void k_pos(const int* __restrict__ idx, int* __restrict__ counts,
                      int* __restrict__ pos) {
    int i = blockIdx.x * blockDim.x + threadIdx.x;
    if (i < NDOM) pos[i] = atomicAdd(&counts[idx[i]], 1);
}

__global__ void k_init_h(float* __restrict__ h, const float* __restrict__ cls) {
    const float4* cls4 = (const float4*)cls;
    float4* h4 = (float4*)h;
    const int total4 = MROWS * DMODEL / 4;
    for (int f = blockIdx.x * blockDim.x + threadIdx.x; f < total4;
         f += gridDim.x * blockDim.x) {
        int d4 = f & 63;
        int t  = (f >> 6) % SEQ;
        h4[f] = (t == 0) ? cls4[d4] : make_float4(0.f, 0.f, 0.f, 0.f);
    }
}

// f32 -> bf16 bulk convert (vectorized)
__global__ void k_b16(const float* __restrict__ x, u16* __restrict__ y, int n4) {
    int i = blockIdx.x * 256 + threadIdx.x;
    if (i < n4) {
        float4 v = ((const float4*)x)[i];
        ushort4 o;
        o.x = f2b(v.x); o.y = f2b(v.y); o.z = f2b(v.z); o.w = f2b(v.w);
        ((ushort4*)y)[i] = o;
    }
}

// merged weight convert+transpose, one 64x64 tile per block, LDS-coalesced.
__global__ __launch_bounds__(256) void k_wt_all(
    const float* __restrict__ projw, const float* __restrict__ qkvw,
    const float* __restrict__ outw,  const float* __restrict__ ff1w,
    const float* __restrict__ ff2w,
    u16* __restrict__ wpj, u16* __restrict__ wq, u16* __restrict__ wo,
    u16* __restrict__ w1,  u16* __restrict__ w2)
{
    __shared__ float t[64][65];
    const int tile = blockIdx.x;
    const float* W; u16* D; int K, N, local;
    if (tile < 8)        { W = projw; D = wpj; K = 128;  N = 256;  local = tile; }
    else if (tile < 200) { int l = (tile-8)/48;   local = (tile-8)%48;
                           W = qkvw + (size_t)l*196608; D = wq + (size_t)l*196608; K = 256;  N = 768; }
    else if (tile < 264) { int l = (tile-200)/16; local = (tile-200)%16;
                           W = outw + (size_t)l*65536;  D = wo + (size_t)l*65536;  K = 256;  N = 256; }
    else if (tile < 520) { int l = (tile-264)/64; local = (tile-264)%64;
                           W = ff1w + (size_t)l*262144; D = w1 + (size_t)l*262144; K = 256;  N = 1024; }
    else                 { int l = (tile-520)/64; local = (tile-520)%64;
                           W = ff2w + (size_t)l*262144; D = w2 + (size_t)l*262144; K = 1024; N = 256; }
    const int ntn = N >> 6;
    const int tk = local / ntn, tn = local % ntn;
    const int r = threadIdx.x >> 6, c = threadIdx.x & 63;
    #pragma unroll 4
    for (int rr = r; rr < 64; rr += 4)
        t[rr][c] = W[(size_t)(tk*64 + rr) * N + tn*64 + c];
    __syncthreads();
    #pragma unroll 4
    for (int rr = r; rr < 64; rr += 4)
        D[(size_t)(tn*64 + rr) * K + tk*64 + c] = f2b(t[c][rr]);
}

// scatter projected rows into padded layout
__global__ __launch_bounds__(256) void k_scatter(
    const float* __restrict__ xp, const int* __restrict__ idx,
    const int* __restrict__ pos, float* __restrict__ h)
{
    const int i = blockIdx.x * 4 + (threadIdx.x >> 6);
    const int lane = threadIdx.x & 63;
    const int p = pos[i] + 1;
    if (p >= SEQ) return;
    const size_t row = (size_t)idx[i] * SEQ + p;
    ((float4*)(h + row * DMODEL))[lane] = ((const float4*)(xp + (size_t)i * DMODEL))[lane];
}

// ---------------- layernorm -> bf16 (layer-0 ln1 only) ----------------

__global__ __launch_bounds__(256) void k_ln_bf(
    const float* __restrict__ x, const float* __restrict__ g,
    const float* __restrict__ bt, u16* __restrict__ y)
{
    const int row  = blockIdx.x * 4 + (threadIdx.x >> 6);
    const int lane = threadIdx.x & 63;
    float4 v = ((const float4*)(x + (size_t)row * DMODEL))[lane];
    float s = v.x + v.y + v.z + v.w;
    #pragma unroll
    for (int off = 32; off >= 1; off >>= 1) s += __shfl_xor(s, off);
    const float m = s * (1.f / DMODEL);
    const float d0 = v.x - m, d1 = v.y - m, d2 = v.z - m, d3 = v.w - m;
    float q = d0*d0 + d1*d1 + d2*d2 + d3*d3;
    #pragma unroll
    for (int off = 32; off >= 1; off >>= 1) q += __shfl_xor(q, off);
    const float rstd = rsqrtf(q * (1.f / DMODEL) + 1e-5f);
    const float4 gv = ((const float4*)g)[lane];
    const float4 bv = ((const float4*)bt)[lane];
    ushort4 o;
    o.x = f2b(d0 * rstd * gv.x + bv.x);
    o.y = f2b(d1 * rstd * gv.y + bv.y);
    o.z = f2b(d2 * rstd * gv.z + bv.z);
    o.w = f2b(d3 * rstd * gv.w + bv.w);
    ((ushort4*)(y + (size_t)row * DMODEL))[lane] = o;
}

// ---------------- bf16 MFMA GEMM (128x128, 4 waves): qkv / ff1 / proj ----------------

template<int RELU, int RESID, int OBF, int OF32>
__global__ __launch_bounds__(256) void k_gemm_bf(
    const u16* __restrict__ A, const u16* __restrict__ Bt,
    const float* __restrict__ bias, float* __restrict__ Cf,
    u16* __restrict__ Cb, int K, int N)
{
    __shared__ u16 As[8192];   // [128][64] bf16, swizzled
    __shared__ u16 Bs[8192];
    const int tid = threadIdx.x;
    const int w = tid >> 6, lane = tid & 63;
    const int lr = lane & 15, lg = lane >> 4;
    const int m0 = blockIdx.y * 128, n0 = blockIdx.x * 128;
    const int wm = (w >> 1) * 64, wn = (w & 1) * 64;

    const f4 zf = {0.f, 0.f, 0.f, 0.f};
    f4 acc[4][4];
    #pragma unroll
    for (int i = 0; i < 4; ++i)
        #pragma unroll
        for (int j = 0; j < 4; ++j) acc[i][j] = zf;

    const int srow8 = lane >> 3;
    const int sq = lane & 7;

    for (int k0 = 0; k0 < K; k0 += 64) {
        #pragma unroll
        for (int c = 0; c < 4; ++c) {
            const int chunk = w * 4 + c;
            const int row = chunk * 8 + srow8;
            const int ks = k0 + ((sq ^ (row & 7)) << 3);
            gload16(A  + (size_t)(m0 + row) * K + ks, (const char*)As + chunk * 1024);
            gload16(Bt + (size_t)(n0 + row) * K + ks, (const char*)Bs + chunk * 1024);
        }
        __syncthreads();
        #pragma unroll
        for (int kk = 0; kk < 2; ++kk) {
            bf8 af[4], bg[4];
            #pragma unroll
            for (int f = 0; f < 4; ++f) {
                const int ra = wm + f * 16 + lr;
                af[f] = *(const bf8*)((const char*)As + ra * 128 +
                        ((((kk << 2) | lg) ^ (ra & 7)) << 4));
                const int rb = wn + f * 16 + lr;
                bg[f] = *(const bf8*)((const char*)Bs + rb * 128 +
                        ((((kk << 2) | lg) ^ (rb & 7)) << 4));
            }
            #pragma unroll
            for (int fm = 0; fm < 4; ++fm)
                #pragma unroll
                for (int fn = 0; fn < 4; ++fn)
                    acc[fm][fn] = __builtin_amdgcn_mfma_f32_16x16x32_bf16(
                        af[fm], bg[fn], acc[fm][fn], 0, 0, 0);
        }
        __syncthreads();
    }

    float bv[4];
    #pragma unroll
    for (int fn = 0; fn < 4; ++fn) bv[fn] = bias[n0 + wn + fn * 16 + lr];
    #pragma unroll
    for (int fm = 0; fm < 4; ++fm)
        #pragma unroll
        for (int j = 0; j < 4; ++j) {
            const int row = m0 + wm + fm * 16 + lg * 4 + j;
            #pragma unroll
            for (int fn = 0; fn < 4; ++fn) {
                float v = acc[fm][fn][j] + bv[fn];
                if (RELU) v = fmaxf(v, 0.f);
                const size_t off = (size_t)row * N + n0 + wn + fn * 16 + lr;
                if (RESID) Cf[off] += v;
                if (OF32)  Cf[off] = v;
                if (OBF)   Cb[off] = f2b(v);
            }
        }
}

// ---------------- fused GEMM(+resid)+LN: 128x256 tile, 8 waves (2Mx4N) ----------------
// h_new = h_old + A@Bt^T + bias;  ybf = LN(h_new) (if LNF). N fixed = 256.

template<int LNF>
__global__ __launch_bounds__(512) void k_gemm_ln(
    const u16* __restrict__ A, const u16* __restrict__ Bt,
    const float* __restrict__ bias, float* __restrict__ h,
    u16* __restrict__ ybf, const float* __restrict__ lng,
    const float* __restrict__ lnb, int K)
{
    __shared__ u16 As[8192];     // [128][64]
    __shared__ u16 Bs[16384];    // [256][64]
    __shared__ float red[8][136];
    const int tid = threadIdx.x;
    const int w = tid >> 6, lane = tid & 63;
    const int lr = lane & 15, lg = lane >> 4;
    const int m0 = blockIdx.x * 128;
    const int wm = (w >> 2) * 64, wn = (w & 3) * 64;

    const f4 zf = {0.f, 0.f, 0.f, 0.f};
    f4 acc[4][4];
    #pragma unroll
    for (int i = 0; i < 4; ++i)
        #pragma unroll
        for (int j = 0; j < 4; ++j) acc[i][j] = zf;

    const int srow8 = lane >> 3;
    const int sq = lane & 7;

    for (int k0 = 0; k0 < K; k0 += 64) {
        #pragma unroll
        for (int c = 0; c < 2; ++c) {
            const int chunk = w * 2 + c;               // 0..15
            const int row = chunk * 8 + srow8;         // 0..127
            const int ks = k0 + ((sq ^ (row & 7)) << 3);
            gload16(A + (size_t)(m0 + row) * K + ks, (const char*)As + chunk * 1024);
        }
        #pragma unroll
        for (int c = 0; c < 4; ++c) {
            const int chunk = w * 4 + c;               // 0..31
            const int row = chunk * 8 + srow8;         // 0..255 (full N)
            const int ks = k0 + ((sq ^ (row & 7)) << 3);
            gload16(Bt + (size_t)row * K + ks, (const char*)Bs + chunk * 1024);
        }
        __syncthreads();
        #pragma unroll
        for (int kk = 0; kk < 2; ++kk) {
            bf8 af[4], bg[4];
            #pragma unroll
            for (int f = 0; f < 4; ++f) {
                const int ra = wm + f * 16 + lr;
                af[f] = *(const bf8*)((const char*)As + ra * 128 +
                        ((((kk << 2) | lg) ^ (ra & 7)) << 4));
                const int rb = wn + f * 16 + lr;
                bg[f] = *(const bf8*)((const char*)Bs + rb * 128 +
                        ((((kk << 2) | lg) ^ (rb & 7)) << 4));
            }
            #pragma unroll
            for (int fm = 0; fm < 4; ++fm)
                #pragma unroll
                for (int fn = 0; fn < 4; ++fn)
                    acc[fm][fn] = __builtin_amdgcn_mfma_f32_16x16x32_bf16(
                        af[fm], bg[fn], acc[fm][fn], 0, 0, 0);
        }
        __syncthreads();
    }

    // epilogue: v = acc + bias + h_old (in place), row stats
    float bv[4];
    #pragma unroll
    for (int fn = 0; fn < 4; ++fn) bv[fn] = bias[wn + fn * 16 + lr];
    float sr[4][4], s2r[4][4];
    #pragma unroll
    for (int fm = 0; fm < 4; ++fm)
        #pragma unroll
        for (int j = 0; j < 4; ++j) {
            const int row = m0 + wm + fm * 16 + lg * 4 + j;
            float s = 0.f, s2 = 0.f;
            #pragma unroll
            for (int fn = 0; fn < 4; ++fn) {
                float v = acc[fm][fn][j] + bv[fn];
                v += h[(size_t)row * DMODEL + wn + fn * 16 + lr];
                acc[fm][fn][j] = v;
                s += v; s2 += v * v;
            }
            if (LNF) {
                #pragma unroll
                for (int off = 1; off <= 8; off <<= 1) {
                    s  += __shfl_xor(s, off);
                    s2 += __shfl_xor(s2, off);
                }
            }
            sr[fm][j] = s; s2r[fm][j] = s2;
        }

    if (LNF) {
        if (lr == 0) {
            #pragma unroll
            for (int fm = 0; fm < 4; ++fm)
                #pragma unroll
                for (int j = 0; j < 4; ++j) {
                    const int rL = wm + fm * 16 + lg * 4 + j;
                    red[(w & 3) * 2 + 0][rL] = sr[fm][j];
                    red[(w & 3) * 2 + 1][rL] = s2r[fm][j];
                }
        }
        __syncthreads();
        float gl[4], bl[4];
        #pragma unroll
        for (int fn = 0; fn < 4; ++fn) {
            gl[fn] = lng[wn + fn * 16 + lr];
            bl[fn] = lnb[wn + fn * 16 + lr];
        }
        #pragma unroll
        for (int fm = 0; fm < 4; ++fm)
            #pragma unroll
            for (int j = 0; j < 4; ++j) {
                const int rL = wm + fm * 16 + lg * 4 + j;
                const int row = m0 + rL;
                const float S  = red[0][rL] + red[2][rL] + red[4][rL] + red[6][rL];
                const float S2 = red[1][rL] + red[3][rL] + red[5][rL] + red[7][rL];
                const float mean = S * (1.f / DMODEL);
                const float var  = S2 * (1.f / DMODEL) - mean * mean;
                const float rstd = rsqrtf(var + 1e-5f);
                #pragma unroll
                for (int fn = 0; fn < 4; ++fn) {
                    const float v = acc[fm][fn][j];
                    const size_t off = (size_t)row * DMODEL + wn + fn * 16 + lr;
                    h[off] = v;
                    ybf[off] = f2b((v - mean) * rstd * gl[fn] + bl[fn]);
                }
            }
    } else {
        #pragma unroll
        for (int fm = 0; fm < 4; ++fm)
            #pragma unroll
            for (int j = 0; j < 4; ++j) {
                const int row = m0 + wm + fm * 16 + lg * 4 + j;
                #pragma unroll
                for (int fn = 0; fn < 4; ++fn)
                    h[(size_t)row * DMODEL + wn + fn * 16 + lr] = acc[fm][fn][j];
            }
    }
}

// ---------------- MFMA flash attention: QBLK=128, 8 waves, XCD-swizzled ----------------

__global__ __launch_bounds__(512) void k_attn_mfma(
    const u16* __restrict__ qkv, const int* __restrict__ counts,
    u16* __restrict__ out)
{
    __shared__ u16 Ks[4096];      // [64 key][64 dh] swizzled
    __shared__ u16 Vt[4096];      // [64 dh][64 key] swizzled
    __shared__ u16 Ps[8][1024];   // per-wave P [16 q][64 key] swizzled
    const int tid = threadIdx.x;
    const int w = tid >> 6, lane = tid & 63;
    const int lr = lane & 15, lg = lane >> 4;
    // XCD swizzle: 24 blocks (6 qt x 4 h) of one batch land on one XCD (L%8)
    const int L = blockIdx.x;
    const int b = (L & 7) * 8 + (L >> 3) / 24;
    const int r = (L >> 3) % 24;
    const int qt = r >> 2, hh = r & 3;
    const int q0 = qt * 128;
    const int kmax = min(counts[b], SEQ - 1);
    if (q0 > kmax) return;                   // dead query tile
    const int ntiles = (kmax + 64) >> 6;
    const size_t bb = (size_t)b * SEQ;

    // Q fragments: q-row = q0 + w*16 + lr, dh = kk*32 + lg*8..+7
    const int qrow = q0 + w * 16 + lr;
    const size_t qoff = (bb + (size_t)min(qrow, SEQ - 1)) * 768 + hh * 64 + (lg << 3);
    const bf8 qf0 = *(const bf8*)(qkv + qoff);
    const bf8 qf1 = *(const bf8*)(qkv + qoff + 32);

    const f4 zf = {0.f, 0.f, 0.f, 0.f};
    f4 o_[4];
    #pragma unroll
    for (int fn = 0; fn < 4; ++fn) o_[fn] = zf;
    float mrow = -INFINITY, ssum = 0.f;

    for (int kt = 0; kt < ntiles; ++kt) {
        const int k0 = kt * 64;
        // stage K tile: 8 waves x 1 chunk (1KB)
        {
            const int row = w * 8 + (lane >> 3);
            const int q = lane & 7;
            const int krow = min(k0 + row, SEQ - 1);
            gload16(qkv + (bb + krow) * 768 + 256 + hh * 64 + ((q ^ (row & 7)) << 3),
                    (const char*)Ks + w * 1024);
        }
        // stage V transposed: 512 threads x (2 keys x 4 dh)
        {
            const int kk2 = (tid & 31) * 2;
            const int dh0 = (tid >> 5) * 4;
            const int r0 = min(k0 + kk2, SEQ - 1), r1 = min(k0 + kk2 + 1, SEQ - 1);
            const ushort4 v0 = *(const ushort4*)(qkv + (bb + r0) * 768 + 512 + hh * 64 + dh0);
            const ushort4 v1 = *(const ushort4*)(qkv + (bb + r1) * 768 + 512 + hh * 64 + dh0);
            const u16* pv0 = (const u16*)&v0;
            const u16* pv1 = (const u16*)&v1;
            #pragma unroll
            for (int e = 0; e < 4; ++e) {
                const int d = dh0 + e;
                const unsigned pk = (unsigned)pv0[e] | ((unsigned)pv1[e] << 16);
                *(unsigned*)((char*)Vt + d * 128 +
                    ((((kk2 >> 3) ^ (d & 7)) << 4)) + ((kk2 & 7) << 1)) = pk;
            }
        }
        __syncthreads();

        // QK^T swapped: lane holds S[q=lr][key = fk*16+lg*4+j]
        f4 sf[4];
        #pragma unroll
        for (int fk = 0; fk < 4; ++fk) sf[fk] = zf;
        #pragma unroll
        for (int kk = 0; kk < 2; ++kk) {
            const bf8 qf = kk ? qf1 : qf0;
            #pragma unroll
            for (int fk = 0; fk < 4; ++fk) {
                const int rk = fk * 16 + lr;
                const bf8 kf = *(const bf8*)((const char*)Ks + rk * 128 +
                        ((((kk << 2) | lg) ^ (rk & 7)) << 4));
                sf[fk] = __builtin_amdgcn_mfma_f32_16x16x32_bf16(kf, qf, sf[fk], 0, 0, 0);
            }
        }

        // online softmax
        float sv[4][4];
        float pmax = -INFINITY;
        if (k0 >= 1 && k0 + 63 <= kmax) {            // interior tile: no masking
            #pragma unroll
            for (int fk = 0; fk < 4; ++fk)
                #pragma unroll
                for (int j = 0; j < 4; ++j) {
                    const float x = sf[fk][j] * 0.125f;
                    sv[fk][j] = x;
                    pmax = fmaxf(pmax, x);
                }
        } else {
            #pragma unroll
            for (int fk = 0; fk < 4; ++fk)
                #pragma unroll
                for (int j = 0; j < 4; ++j) {
                    const int key = k0 + fk * 16 + lg * 4 + j;
                    const float x = (key >= 1 && key <= kmax) ? sf[fk][j] * 0.125f : -INFINITY;
                    sv[fk][j] = x;
                    pmax = fmaxf(pmax, x);
                }
        }
        pmax = fmaxf(pmax, __shfl_xor(pmax, 16));
        pmax = fmaxf(pmax, __shfl_xor(pmax, 32));
        const float mnew = fmaxf(mrow, pmax);
        const float fac = __expf(mrow - mnew);
        mrow = mnew;
        float tsum = 0.f;
        #pragma unroll
        for (int fk = 0; fk < 4; ++fk) {
            const float p0 = __expf(sv[fk][0] - mnew);
            const float p1 = __expf(sv[fk][1] - mnew);
            const float p2 = __expf(sv[fk][2] - mnew);
            const float p3 = __expf(sv[fk][3] - mnew);
            tsum += p0 + p1 + p2 + p3;
            ushort4 pk;
            pk.x = f2b(p0); pk.y = f2b(p1); pk.z = f2b(p2); pk.w = f2b(p3);
            *(ushort4*)((char*)Ps[w] + lr * 128 +
                (((((fk << 1) | (lg >> 1)) ^ (lr & 7)) << 4)) + ((lg & 1) << 3)) = pk;
        }
        tsum += __shfl_xor(tsum, 16);
        tsum += __shfl_xor(tsum, 32);
        ssum = ssum * fac + tsum;

        #pragma unroll
        for (int j = 0; j < 4; ++j) {
            const float fj = __shfl(fac, lg * 4 + j);
            #pragma unroll
            for (int fn = 0; fn < 4; ++fn) o_[fn][j] *= fj;
        }
        __syncthreads();

        // PV
        #pragma unroll
        for (int kk = 0; kk < 2; ++kk) {
            const bf8 pa = *(const bf8*)((const char*)Ps[w] + lr * 128 +
                    ((((kk << 2) | lg) ^ (lr & 7)) << 4));
            #pragma unroll
            for (int fn = 0; fn < 4; ++fn) {
                const int rv = fn * 16 + lr;
                const bf8 vf = *(const bf8*)((const char*)Vt + rv * 128 +
                        ((((kk << 2) | lg) ^ (rv & 7)) << 4));
                o_[fn] = __builtin_amdgcn_mfma_f32_16x16x32_bf16(pa, vf, o_[fn], 0, 0, 0);
            }
        }
        __syncthreads();
    }

    const float inv = 1.f / ssum;
    #pragma unroll
    for (int j = 0; j < 4; ++j) {
        const float ij = __shfl(inv, lg * 4 + j);
        const int qr = q0 + w * 16 + lg * 4 + j;
        if (qr < SEQ) {
            #pragma unroll
            for (int fn = 0; fn < 4; ++fn)
                out[(bb + qr) * DMODEL + hh * 64 + fn * 16 + lr] = f2b(o_[fn][j] * ij);
        }
    }
}

// ---------------- head ----------------

__global__ __launch_bounds__(256) void k_head(
    const float* __restrict__ h, const float* __restrict__ w1,
    const float* __restrict__ b1, const float* __restrict__ w2,
    const float* __restrict__ b2, float* __restrict__ out)
{
    __shared__ float cbuf[DMODEL];
    __shared__ float p1[DMODEL];
    __shared__ float p2[3];
    const int b = blockIdx.x, tid = threadIdx.x;
    cbuf[tid] = h[(size_t)b * SEQ * DMODEL + tid];
    __syncthreads();
    float acc = b1[tid];
    #pragma unroll 8
    for (int k = 0; k < DMODEL; ++k) acc = fmaf(cbuf[k], w1[k * DMODEL + tid], acc);
    p1[tid] = fmaxf(acc, 0.f);
    __syncthreads();
    if (tid < 3) {
        float a = b2[tid];
        for (int k = 0; k < DMODEL; ++k) a = fmaf(p1[k], w2[k * 3 + tid], a);
        p2[tid] = a;
    }
    __syncthreads();
    if (tid < 3) {
        float n2 = p2[0]*p2[0] + p2[1]*p2[1] + p2[2]*p2[2];
        out[b * 3 + tid] = p2[tid] * rsqrtf(n2);
    }
}

// ---------------- launch ----------------

extern "C" void kernel_launch(void* const* d_in, const int* in_sizes, int n_in,
                              void* d_out, int out_size, void* d_ws, size_t ws_size,
                              hipStream_t stream) {
    const float* emb   = (const float*)d_in[0];
    const int*   idx   = (const int*)d_in[1];
    const float* projw = (const float*)d_in[4];
    const float* projb = (const float*)d_in[5];
    const float* cls   = (const float*)d_in[6];
    const float* ln1g  = (const float*)d_in[7];
    const float* ln1b  = (const float*)d_in[8];
    const float* qkvw  = (const float*)d_in[9];
    const float* qkvb  = (const float*)d_in[10];
    const float* outw  = (const float*)d_in[11];
    const float* outb  = (const float*)d_in[12];
    const float* ln2g  = (const float*)d_in[13];
    const float* ln2b  = (const float*)d_in[14];
    const float* ff1w  = (const float*)d_in[15];
    const float* ff1b  = (const float*)d_in[16];
    const float* ff2w  = (const float*)d_in[17];
    const float* ff2b  = (const float*)d_in[18];
    const float* h1w   = (const float*)d_in[19];
    const float* h1b   = (const float*)d_in[20];
    const float* h2w   = (const float*)d_in[21];
    const float* h2b   = (const float*)d_in[22];
    float* out = (float*)d_out;

    char* ws = (char*)d_ws;
    int*   counts = (int*)ws;                               // @0
    int*   pos    = (int*)(ws + 4096);
    float* h      = (float*)(ws + 135168);                  // [M][256] f32
    u16*   ybf    = (u16*)(ws + 44175360);                  // [M][256] bf16
    u16*   qkvb16 = (u16*)(ws + 66195456);                  // [M+64][768] bf16
    u16*   ffb    = (u16*)(ws + 132354048);                 // [M][1024] bf16
    u16*   wq     = (u16*)(ws + 220434432);                 // 4 x [768][256]
    u16*   wo     = (u16*)(ws + 222007296);                 // 4 x [256][256]
    u16*   w1     = (u16*)(ws + 222531584);                 // 4 x [1024][256]
    u16*   w2     = (u16*)(ws + 224628736);                 // 4 x [256][1024]
    u16*   wpj    = (u16*)(ws + 226725888);                 // [256][128]
    u16*   embbf  = qkvb16;                                 // alias (pre-loop)
    float* xp     = (float*)ffb;                            // alias (pre-loop)

    k_zero_counts<<<1, 64, 0, stream>>>(counts);
    k_pos<<<NDOM / 256, 256, 0, stream>>>(idx, counts, pos);
    k_b16<<<(NDOM * DIN / 4) / 256, 256, 0, stream>>>(emb, embbf, NDOM * DIN / 4);
    k_wt_all<<<776, 256, 0, stream>>>(projw, qkvw, outw, ff1w, ff2w,
                                      wpj, wq, wo, w1, w2);
    k_init_h<<<2688, 256, 0, stream>>>(h, cls);
    k_gemm_bf<0,0,0,1><<<dim3(2, 256), 256, 0, stream>>>(
        embbf, wpj, projb, xp, nullptr, DIN, DMODEL);
    k_scatter<<<NDOM / 4, 256, 0, stream>>>(xp, idx, pos, h);
    k_ln_bf<<<MROWS / 4, 256, 0, stream>>>(h, ln1g, ln1b, ybf);

    for (int l = 0; l < NLAYER; ++l) {
        k_gemm_bf<0,0,1,0><<<dim3(6, 336), 256, 0, stream>>>(
            ybf, wq + (size_t)l * 196608, qkvb + l * 768, nullptr, qkvb16, 256, 768);
        k_attn_mfma<<<1536, 512, 0, stream>>>(qkvb16, counts, ybf);
        k_gemm_ln<1><<<336, 512, 0, stream>>>(
            ybf, wo + (size_t)l * 65536, outb + l * DMODEL, h, ybf,
            ln2g + l * DMODEL, ln2b + l * DMODEL, 256);
        k_gemm_bf<1,0,1,0><<<dim3(8, 336), 256, 0, stream>>>(
            ybf, w1 + (size_t)l * 262144, ff1b + l * DFFN, nullptr, ffb, 256, 1024);
        if (l < NLAYER - 1)
            k_gemm_ln<1><<<336, 512, 0, stream>>>(
                ffb, w2 + (size_t)l * 262144, ff2b + l * DMODEL, h, ybf,
                ln1g + (l + 1) * DMODEL, ln1b + (l + 1) * DMODEL, 1024);
        else
            k_gemm_ln<0><<<336, 512, 0, stream>>>(
                ffb, w2 + (size_t)l * 262144, ff2b + l * DMODEL, h, nullptr,
                nullptr, nullptr, 1024);
    }

    k_head<<<BATCH, 256, 0, stream>>>(h, h1w, h1b, h2w, h2b, out);
}

// Round 7
// 1085.886 us; speedup vs baseline: 1.0902x; 1.0902x over previous
//
#include <hip/hip_runtime.h>
#include <cstdint>
#include <cstddef>

#define NDOM   32768
#define DIN    128
#define DMODEL 256
#define NHEAD  4
#define NLAYER 4
#define DFFN   1024
#define BATCH  64
#define SEQ    672
#define DHEAD  64
#define MC     33024   // compact rows padded: 32832 live (NDOM+BATCH) + scratch tail
#define MTILES 258     // MC/128

typedef unsigned short u16;
typedef __attribute__((ext_vector_type(8))) short bf8;   // 8 bf16 (4 VGPRs)
typedef __attribute__((ext_vector_type(4))) float f4;    // MFMA accumulator

__device__ inline u16 f2b(float x) {            // f32 -> bf16 RNE
    union { float f; unsigned u; } c; c.f = x;
    unsigned r = c.u + 0x7fffu + ((c.u >> 16) & 1u);
    return (u16)(r >> 16);
}

__device__ inline void gload16(const void* g, const void* l) {
    __builtin_amdgcn_global_load_lds(
        (const __attribute__((address_space(1))) void*)g,
        (__attribute__((address_space(3))) void*)l, 16, 0, 0);
}

// ---------------- setup ----------------

__global__ void k_zero_counts(int* __restrict__ counts) {
    if (threadIdx.x < BATCH) counts[threadIdx.x] = 0;
}

__global__ void k_pos(const int* __restrict__ idx, int* __restrict__ counts,
                      int* __restrict__ pos) {
    int i = blockIdx.x * blockDim.x + threadIdx.x;
    if (i < NDOM) pos[i] = atomicAdd(&counts[idx[i]], 1);
}

// segment bases via wave prefix-sum: base[b] = b + sum_{j<b} counts[j]
__global__ void k_base(const int* __restrict__ counts, int* __restrict__ base) {
    const int lane = threadIdx.x;
    const int c = counts[lane];
    int s = c;
    #pragma unroll
    for (int off = 1; off < 64; off <<= 1) {
        int t = __shfl_up(s, off);
        if (lane >= off) s += t;
    }
    base[lane] = lane + (s - c);
    if (lane == 63) base[64] = 64 + s;
}

// rmap[i] = compact row of dom i
__global__ void k_rmap(const int* __restrict__ idx, const int* __restrict__ pos,
                       const int* __restrict__ base, int* __restrict__ rmap) {
    int i = blockIdx.x * 256 + threadIdx.x;
    if (i < NDOM) {
        int p = pos[i] + 1;
        rmap[i] = (p < SEQ) ? base[idx[i]] + p : (MC - 1);  // overflow -> scratch row
    }
}

__global__ void k_init_cls(const int* __restrict__ base, const float* __restrict__ cls,
                           float* __restrict__ h) {
    h[(size_t)base[blockIdx.x] * DMODEL + threadIdx.x] = cls[threadIdx.x];
}

// f32 -> bf16 bulk convert (vectorized)
__global__ void k_b16(const float* __restrict__ x, u16* __restrict__ y, int n4) {
    int i = blockIdx.x * 256 + threadIdx.x;
    if (i < n4) {
        float4 v = ((const float4*)x)[i];
        ushort4 o;
        o.x = f2b(v.x); o.y = f2b(v.y); o.z = f2b(v.z); o.w = f2b(v.w);
        ((ushort4*)y)[i] = o;
    }
}

// merged weight convert+transpose, one 64x64 tile per block, LDS-coalesced.
__global__ __launch_bounds__(256) void k_wt_all(
    const float* __restrict__ projw, const float* __restrict__ qkvw,
    const float* __restrict__ outw,  const float* __restrict__ ff1w,
    const float* __restrict__ ff2w,
    u16* __restrict__ wpj, u16* __restrict__ wq, u16* __restrict__ wo,
    u16* __restrict__ w1,  u16* __restrict__ w2)
{
    __shared__ float t[64][65];
    const int tile = blockIdx.x;
    const float* W; u16* D; int K, N, local;
    if (tile < 8)        { W = projw; D = wpj; K = 128;  N = 256;  local = tile; }
    else if (tile < 200) { int l = (tile-8)/48;   local = (tile-8)%48;
                           W = qkvw + (size_t)l*196608; D = wq + (size_t)l*196608; K = 256;  N = 768; }
    else if (tile < 264) { int l = (tile-200)/16; local = (tile-200)%16;
                           W = outw + (size_t)l*65536;  D = wo + (size_t)l*65536;  K = 256;  N = 256; }
    else if (tile < 520) { int l = (tile-264)/64; local = (tile-264)%64;
                           W = ff1w + (size_t)l*262144; D = w1 + (size_t)l*262144; K = 256;  N = 1024; }
    else                 { int l = (tile-520)/64; local = (tile-520)%64;
                           W = ff2w + (size_t)l*262144; D = w2 + (size_t)l*262144; K = 1024; N = 256; }
    const int ntn = N >> 6;
    const int tk = local / ntn, tn = local % ntn;
    const int r = threadIdx.x >> 6, c = threadIdx.x & 63;
    #pragma unroll 4
    for (int rr = r; rr < 64; rr += 4)
        t[rr][c] = W[(size_t)(tk*64 + rr) * N + tn*64 + c];
    __syncthreads();
    #pragma unroll 4
    for (int rr = r; rr < 64; rr += 4)
        D[(size_t)(tn*64 + rr) * K + tk*64 + c] = f2b(t[c][rr]);
}

// ---------------- layernorm -> bf16 (layer-0 ln1 only) ----------------

__global__ __launch_bounds__(256) void k_ln_bf(
    const float* __restrict__ x, const float* __restrict__ g,
    const float* __restrict__ bt, u16* __restrict__ y)
{
    const int row  = blockIdx.x * 4 + (threadIdx.x >> 6);
    const int lane = threadIdx.x & 63;
    float4 v = ((const float4*)(x + (size_t)row * DMODEL))[lane];
    float s = v.x + v.y + v.z + v.w;
    #pragma unroll
    for (int off = 32; off >= 1; off >>= 1) s += __shfl_xor(s, off);
    const float m = s * (1.f / DMODEL);
    const float d0 = v.x - m, d1 = v.y - m, d2 = v.z - m, d3 = v.w - m;
    float q = d0*d0 + d1*d1 + d2*d2 + d3*d3;
    #pragma unroll
    for (int off = 32; off >= 1; off >>= 1) q += __shfl_xor(q, off);
    const float rstd = rsqrtf(q * (1.f / DMODEL) + 1e-5f);
    const float4 gv = ((const float4*)g)[lane];
    const float4 bv = ((const float4*)bt)[lane];
    ushort4 o;
    o.x = f2b(d0 * rstd * gv.x + bv.x);
    o.y = f2b(d1 * rstd * gv.y + bv.y);
    o.z = f2b(d2 * rstd * gv.z + bv.z);
    o.w = f2b(d3 * rstd * gv.w + bv.w);
    ((ushort4*)(y + (size_t)row * DMODEL))[lane] = o;
}

// ---------------- bf16 MFMA GEMM (128x128, 4 waves): qkv / ff1 / proj ----------------

template<int RELU, int OBF, int OF32, int SCAT>
__global__ __launch_bounds__(256) void k_gemm_bf(
    const u16* __restrict__ A, const u16* __restrict__ Bt,
    const float* __restrict__ bias, float* __restrict__ Cf,
    u16* __restrict__ Cb, const int* __restrict__ rmap, int K, int N)
{
    __shared__ u16 As[8192];   // [128][64] bf16, swizzled
    __shared__ u16 Bs[8192];
    const int tid = threadIdx.x;
    const int w = tid >> 6, lane = tid & 63;
    const int lr = lane & 15, lg = lane >> 4;
    const int m0 = blockIdx.y * 128, n0 = blockIdx.x * 128;
    const int wm = (w >> 1) * 64, wn = (w & 1) * 64;

    const f4 zf = {0.f, 0.f, 0.f, 0.f};
    f4 acc[4][4];
    #pragma unroll
    for (int i = 0; i < 4; ++i)
        #pragma unroll
        for (int j = 0; j < 4; ++j) acc[i][j] = zf;

    const int srow8 = lane >> 3;
    const int sq = lane & 7;

    for (int k0 = 0; k0 < K; k0 += 64) {
        #pragma unroll
        for (int c = 0; c < 4; ++c) {
            const int chunk = w * 4 + c;
            const int row = chunk * 8 + srow8;
            const int ks = k0 + ((sq ^ (row & 7)) << 3);
            gload16(A  + (size_t)(m0 + row) * K + ks, (const char*)As + chunk * 1024);
            gload16(Bt + (size_t)(n0 + row) * K + ks, (const char*)Bs + chunk * 1024);
        }
        __syncthreads();
        #pragma unroll
        for (int kk = 0; kk < 2; ++kk) {
            bf8 af[4], bg[4];
            #pragma unroll
            for (int f = 0; f < 4; ++f) {
                const int ra = wm + f * 16 + lr;
                af[f] = *(const bf8*)((const char*)As + ra * 128 +
                        ((((kk << 2) | lg) ^ (ra & 7)) << 4));
                const int rb = wn + f * 16 + lr;
                bg[f] = *(const bf8*)((const char*)Bs + rb * 128 +
                        ((((kk << 2) | lg) ^ (rb & 7)) << 4));
            }
            #pragma unroll
            for (int fm = 0; fm < 4; ++fm)
                #pragma unroll
                for (int fn = 0; fn < 4; ++fn)
                    acc[fm][fn] = __builtin_amdgcn_mfma_f32_16x16x32_bf16(
                        af[fm], bg[fn], acc[fm][fn], 0, 0, 0);
        }
        __syncthreads();
    }

    float bv[4];
    #pragma unroll
    for (int fn = 0; fn < 4; ++fn) bv[fn] = bias[n0 + wn + fn * 16 + lr];
    #pragma unroll
    for (int fm = 0; fm < 4; ++fm)
        #pragma unroll
        for (int j = 0; j < 4; ++j) {
            const int row = m0 + wm + fm * 16 + lg * 4 + j;
            const int orow = SCAT ? rmap[row] : row;
            #pragma unroll
            for (int fn = 0; fn < 4; ++fn) {
                float v = acc[fm][fn][j] + bv[fn];
                if (RELU) v = fmaxf(v, 0.f);
                const size_t off = (size_t)orow * N + n0 + wn + fn * 16 + lr;
                if (OF32)  Cf[off] = v;
                if (OBF)   Cb[off] = f2b(v);
            }
        }
}

// ---------------- fused GEMM(+resid)+LN: 128x256 tile, 8 waves (2Mx4N) ----------------
// h_new = h_old + A@Bt^T + bias;  ybf = LN(h_new) (if LNF). N fixed = 256.

template<int LNF>
__global__ __launch_bounds__(512) void k_gemm_ln(
    const u16* __restrict__ A, const u16* __restrict__ Bt,
    const float* __restrict__ bias, float* __restrict__ h,
    u16* __restrict__ ybf, const float* __restrict__ lng,
    const float* __restrict__ lnb, int K)
{
    __shared__ u16 As[8192];     // [128][64]
    __shared__ u16 Bs[16384];    // [256][64]
    __shared__ float red[8][136];
    const int tid = threadIdx.x;
    const int w = tid >> 6, lane = tid & 63;
    const int lr = lane & 15, lg = lane >> 4;
    const int m0 = blockIdx.x * 128;
    const int wm = (w >> 2) * 64, wn = (w & 3) * 64;

    const f4 zf = {0.f, 0.f, 0.f, 0.f};
    f4 acc[4][4];
    #pragma unroll
    for (int i = 0; i < 4; ++i)
        #pragma unroll
        for (int j = 0; j < 4; ++j) acc[i][j] = zf;

    const int srow8 = lane >> 3;
    const int sq = lane & 7;

    for (int k0 = 0; k0 < K; k0 += 64) {
        #pragma unroll
        for (int c = 0; c < 2; ++c) {
            const int chunk = w * 2 + c;               // 0..15
            const int row = chunk * 8 + srow8;         // 0..127
            const int ks = k0 + ((sq ^ (row & 7)) << 3);
            gload16(A + (size_t)(m0 + row) * K + ks, (const char*)As + chunk * 1024);
        }
        #pragma unroll
        for (int c = 0; c < 4; ++c) {
            const int chunk = w * 4 + c;               // 0..31
            const int row = chunk * 8 + srow8;         // 0..255
            const int ks = k0 + ((sq ^ (row & 7)) << 3);
            gload16(Bt + (size_t)row * K + ks, (const char*)Bs + chunk * 1024);
        }
        __syncthreads();
        #pragma unroll
        for (int kk = 0; kk < 2; ++kk) {
            bf8 af[4], bg[4];
            #pragma unroll
            for (int f = 0; f < 4; ++f) {
                const int ra = wm + f * 16 + lr;
                af[f] = *(const bf8*)((const char*)As + ra * 128 +
                        ((((kk << 2) | lg) ^ (ra & 7)) << 4));
                const int rb = wn + f * 16 + lr;
                bg[f] = *(const bf8*)((const char*)Bs + rb * 128 +
                        ((((kk << 2) | lg) ^ (rb & 7)) << 4));
            }
            #pragma unroll
            for (int fm = 0; fm < 4; ++fm)
                #pragma unroll
                for (int fn = 0; fn < 4; ++fn)
                    acc[fm][fn] = __builtin_amdgcn_mfma_f32_16x16x32_bf16(
                        af[fm], bg[fn], acc[fm][fn], 0, 0, 0);
        }
        __syncthreads();
    }

    float bv[4];
    #pragma unroll
    for (int fn = 0; fn < 4; ++fn) bv[fn] = bias[wn + fn * 16 + lr];
    float sr[4][4], s2r[4][4];
    #pragma unroll
    for (int fm = 0; fm < 4; ++fm)
        #pragma unroll
        for (int j = 0; j < 4; ++j) {
            const int row = m0 + wm + fm * 16 + lg * 4 + j;
            float s = 0.f, s2 = 0.f;
            #pragma unroll
            for (int fn = 0; fn < 4; ++fn) {
                float v = acc[fm][fn][j] + bv[fn];
                v += h[(size_t)row * DMODEL + wn + fn * 16 + lr];
                acc[fm][fn][j] = v;
                s += v; s2 += v * v;
            }
            if (LNF) {
                #pragma unroll
                for (int off = 1; off <= 8; off <<= 1) {
                    s  += __shfl_xor(s, off);
                    s2 += __shfl_xor(s2, off);
                }
            }
            sr[fm][j] = s; s2r[fm][j] = s2;
        }

    if (LNF) {
        if (lr == 0) {
            #pragma unroll
            for (int fm = 0; fm < 4; ++fm)
                #pragma unroll
                for (int j = 0; j < 4; ++j) {
                    const int rL = wm + fm * 16 + lg * 4 + j;
                    red[(w & 3) * 2 + 0][rL] = sr[fm][j];
                    red[(w & 3) * 2 + 1][rL] = s2r[fm][j];
                }
        }
        __syncthreads();
        float gl[4], bl[4];
        #pragma unroll
        for (int fn = 0; fn < 4; ++fn) {
            gl[fn] = lng[wn + fn * 16 + lr];
            bl[fn] = lnb[wn + fn * 16 + lr];
        }
        #pragma unroll
        for (int fm = 0; fm < 4; ++fm)
            #pragma unroll
            for (int j = 0; j < 4; ++j) {
                const int rL = wm + fm * 16 + lg * 4 + j;
                const int row = m0 + rL;
                const float S  = red[0][rL] + red[2][rL] + red[4][rL] + red[6][rL];
                const float S2 = red[1][rL] + red[3][rL] + red[5][rL] + red[7][rL];
                const float mean = S * (1.f / DMODEL);
                const float var  = S2 * (1.f / DMODEL) - mean * mean;
                const float rstd = rsqrtf(var + 1e-5f);
                #pragma unroll
                for (int fn = 0; fn < 4; ++fn) {
                    const float v = acc[fm][fn][j];
                    const size_t off = (size_t)row * DMODEL + wn + fn * 16 + lr;
                    h[off] = v;
                    ybf[off] = f2b((v - mean) * rstd * gl[fn] + bl[fn]);
                }
            }
    } else {
        #pragma unroll
        for (int fm = 0; fm < 4; ++fm)
            #pragma unroll
            for (int j = 0; j < 4; ++j) {
                const int row = m0 + wm + fm * 16 + lg * 4 + j;
                #pragma unroll
                for (int fn = 0; fn < 4; ++fn)
                    h[(size_t)row * DMODEL + wn + fn * 16 + lr] = acc[fm][fn][j];
            }
    }
}

// ---------------- MFMA flash attention on compact segments ----------------
// Segment of batch b: rows base[b] .. base[b]+count[b] (row 0 = CLS).
// Keys valid iff 1 <= t <= count[b] (segment-relative). QBLK=128, 8 waves.

__global__ __launch_bounds__(512) void k_attn_mfma(
    const u16* __restrict__ qkv, const int* __restrict__ counts,
    const int* __restrict__ base, u16* __restrict__ out)
{
    __shared__ u16 Ks[4096];      // [64 key][64 dh] swizzled
    __shared__ u16 Vt[4096];      // [64 dh][64 key] swizzled
    __shared__ u16 Ps[8][1024];   // per-wave P [16 q][64 key] swizzled
    const int tid = threadIdx.x;
    const int w = tid >> 6, lane = tid & 63;
    const int lr = lane & 15, lg = lane >> 4;
    // XCD swizzle: 24 blocks (6 qt x 4 h) of one batch land on one XCD (L%8)
    const int L = blockIdx.x;
    const int b = (L & 7) * 8 + (L >> 3) / 24;
    const int r = (L >> 3) % 24;
    const int qt = r >> 2, hh = r & 3;
    const int q0 = qt * 128;
    const int kmax = min(counts[b], SEQ - 1);
    if (q0 > kmax) return;                   // dead query tile
    const int ntiles = (kmax + 64) >> 6;
    const size_t bb = (size_t)base[b];

    // Q fragments: q-row (segment) = q0 + w*16 + lr, dh = kk*32 + lg*8..+7
    const int qrow = q0 + w * 16 + lr;
    const size_t qoff = (bb + qrow) * 768 + hh * 64 + (lg << 3);
    const bf8 qf0 = *(const bf8*)(qkv + qoff);
    const bf8 qf1 = *(const bf8*)(qkv + qoff + 32);

    const f4 zf = {0.f, 0.f, 0.f, 0.f};
    f4 o_[4];
    #pragma unroll
    for (int fn = 0; fn < 4; ++fn) o_[fn] = zf;
    float mrow = -INFINITY, ssum = 0.f;

    for (int kt = 0; kt < ntiles; ++kt) {
        const int k0 = kt * 64;
        // stage K tile: 8 waves x 1 chunk (1KB)
        {
            const int row = w * 8 + (lane >> 3);
            const int q = lane & 7;
            gload16(qkv + (bb + k0 + row) * 768 + 256 + hh * 64 + ((q ^ (row & 7)) << 3),
                    (const char*)Ks + w * 1024);
        }
        // stage V transposed: 512 threads x (2 keys x 4 dh)
        {
            const int kk2 = (tid & 31) * 2;
            const int dh0 = (tid >> 5) * 4;
            const ushort4 v0 = *(const ushort4*)(qkv + (bb + k0 + kk2) * 768 + 512 + hh * 64 + dh0);
            const ushort4 v1 = *(const ushort4*)(qkv + (bb + k0 + kk2 + 1) * 768 + 512 + hh * 64 + dh0);
            const u16* pv0 = (const u16*)&v0;
            const u16* pv1 = (const u16*)&v1;
            #pragma unroll
            for (int e = 0; e < 4; ++e) {
                const int d = dh0 + e;
                const unsigned pk = (unsigned)pv0[e] | ((unsigned)pv1[e] << 16);
                *(unsigned*)((char*)Vt + d * 128 +
                    ((((kk2 >> 3) ^ (d & 7)) << 4)) + ((kk2 & 7) << 1)) = pk;
            }
        }
        __syncthreads();

        // QK^T swapped: lane holds S[q=lr][key = fk*16+lg*4+j]
        f4 sf[4];
        #pragma unroll
        for (int fk = 0; fk < 4; ++fk) sf[fk] = zf;
        #pragma unroll
        for (int kk = 0; kk < 2; ++kk) {
            const bf8 qf = kk ? qf1 : qf0;
            #pragma unroll
            for (int fk = 0; fk < 4; ++fk) {
                const int rk = fk * 16 + lr;
                const bf8 kf = *(const bf8*)((const char*)Ks + rk * 128 +
                        ((((kk << 2) | lg) ^ (rk & 7)) << 4));
                sf[fk] = __builtin_amdgcn_mfma_f32_16x16x32_bf16(kf, qf, sf[fk], 0, 0, 0);
            }
        }

        // online softmax (stats per q-row lr, replicated across 4 lane-groups)
        float sv[4][4];
        float pmax = -INFINITY;
        if (k0 >= 1 && k0 + 63 <= kmax) {            // interior tile: no masking
            #pragma unroll
            for (int fk = 0; fk < 4; ++fk)
                #pragma unroll
                for (int j = 0; j < 4; ++j) {
                    const float x = sf[fk][j] * 0.125f;
                    sv[fk][j] = x;
                    pmax = fmaxf(pmax, x);
                }
        } else {
            #pragma unroll
            for (int fk = 0; fk < 4; ++fk)
                #pragma unroll
                for (int j = 0; j < 4; ++j) {
                    const int key = k0 + fk * 16 + lg * 4 + j;
                    const float x = (key >= 1 && key <= kmax) ? sf[fk][j] * 0.125f : -INFINITY;
                    sv[fk][j] = x;
                    pmax = fmaxf(pmax, x);
                }
        }
        pmax = fmaxf(pmax, __shfl_xor(pmax, 16));
        pmax = fmaxf(pmax, __shfl_xor(pmax, 32));

        // defer-max (T13): only rescale when the running max grew by > 8
        if (!__all(pmax <= mrow + 8.f)) {
            const float mnew = fmaxf(mrow, pmax);
            const float fac = __expf(mrow - mnew);   // 0 on first tile
            mrow = mnew;
            ssum *= fac;
            #pragma unroll
            for (int j = 0; j < 4; ++j) {
                const float fj = __shfl(fac, lg * 4 + j);
                #pragma unroll
                for (int fn = 0; fn < 4; ++fn) o_[fn][j] *= fj;
            }
        }

        float tsum = 0.f;
        #pragma unroll
        for (int fk = 0; fk < 4; ++fk) {
            const float p0 = __expf(sv[fk][0] - mrow);
            const float p1 = __expf(sv[fk][1] - mrow);
            const float p2 = __expf(sv[fk][2] - mrow);
            const float p3 = __expf(sv[fk][3] - mrow);
            tsum += p0 + p1 + p2 + p3;
            ushort4 pk;
            pk.x = f2b(p0); pk.y = f2b(p1); pk.z = f2b(p2); pk.w = f2b(p3);
            *(ushort4*)((char*)Ps[w] + lr * 128 +
                (((((fk << 1) | (lg >> 1)) ^ (lr & 7)) << 4)) + ((lg & 1) << 3)) = pk;
        }
        tsum += __shfl_xor(tsum, 16);
        tsum += __shfl_xor(tsum, 32);
        ssum += tsum;
        __syncthreads();   // P visible

        // PV
        #pragma unroll
        for (int kk = 0; kk < 2; ++kk) {
            const bf8 pa = *(const bf8*)((const char*)Ps[w] + lr * 128 +
                    ((((kk << 2) | lg) ^ (lr & 7)) << 4));
            #pragma unroll
            for (int fn = 0; fn < 4; ++fn) {
                const int rv = fn * 16 + lr;
                const bf8 vf = *(const bf8*)((const char*)Vt + rv * 128 +
                        ((((kk << 2) | lg) ^ (rv & 7)) << 4));
                o_[fn] = __builtin_amdgcn_mfma_f32_16x16x32_bf16(pa, vf, o_[fn], 0, 0, 0);
            }
        }
        __syncthreads();   // everyone done with Ks/Vt/Ps before next stage
    }

    const float inv = 1.f / ssum;
    #pragma unroll
    for (int j = 0; j < 4; ++j) {
        const float ij = __shfl(inv, lg * 4 + j);
        const int qr = q0 + w * 16 + lg * 4 + j;
        if (qr <= kmax) {   // live rows only (don't cross into next segment)
            #pragma unroll
            for (int fn = 0; fn < 4; ++fn)
                out[(bb + qr) * DMODEL + hh * 64 + fn * 16 + lr] = f2b(o_[fn][j] * ij);
        }
    }
}

// ---------------- head ----------------

__global__ __launch_bounds__(256) void k_head(
    const float* __restrict__ h, const int* __restrict__ base,
    const float* __restrict__ w1, const float* __restrict__ b1,
    const float* __restrict__ w2, const float* __restrict__ b2,
    float* __restrict__ out)
{
    __shared__ float cbuf[DMODEL];
    __shared__ float p1[DMODEL];
    __shared__ float p2[3];
    const int b = blockIdx.x, tid = threadIdx.x;
    cbuf[tid] = h[(size_t)base[b] * DMODEL + tid];
    __syncthreads();
    float acc = b1[tid];
    #pragma unroll 8
    for (int k = 0; k < DMODEL; ++k) acc = fmaf(cbuf[k], w1[k * DMODEL + tid], acc);
    p1[tid] = fmaxf(acc, 0.f);
    __syncthreads();
    if (tid < 3) {
        float a = b2[tid];
        for (int k = 0; k < DMODEL; ++k) a = fmaf(p1[k], w2[k * 3 + tid], a);
        p2[tid] = a;
    }
    __syncthreads();
    if (tid < 3) {
        float n2 = p2[0]*p2[0] + p2[1]*p2[1] + p2[2]*p2[2];
        out[b * 3 + tid] = p2[tid] * rsqrtf(n2);
    }
}

// ---------------- launch ----------------

extern "C" void kernel_launch(void* const* d_in, const int* in_sizes, int n_in,
                              void* d_out, int out_size, void* d_ws, size_t ws_size,
                              hipStream_t stream) {
    const float* emb   = (const float*)d_in[0];
    const int*   idx   = (const int*)d_in[1];
    const float* projw = (const float*)d_in[4];
    const float* projb = (const float*)d_in[5];
    const float* cls   = (const float*)d_in[6];
    const float* ln1g  = (const float*)d_in[7];
    const float* ln1b  = (const float*)d_in[8];
    const float* qkvw  = (const float*)d_in[9];
    const float* qkvb  = (const float*)d_in[10];
    const float* outw  = (const float*)d_in[11];
    const float* outb  = (const float*)d_in[12];
    const float* ln2g  = (const float*)d_in[13];
    const float* ln2b  = (const float*)d_in[14];
    const float* ff1w  = (const float*)d_in[15];
    const float* ff1b  = (const float*)d_in[16];
    const float* ff2w  = (const float*)d_in[17];
    const float* ff2b  = (const float*)d_in[18];
    const float* h1w   = (const float*)d_in[19];
    const float* h1b   = (const float*)d_in[20];
    const float* h2w   = (const float*)d_in[21];
    const float* h2b   = (const float*)d_in[22];
    float* out = (float*)d_out;

    char* ws = (char*)d_ws;
    int*   counts = (int*)ws;                               // @0
    int*   base   = (int*)(ws + 256);                       // 65 ints
    int*   pos    = (int*)(ws + 1024);                      // NDOM
    int*   rmap   = (int*)(ws + 132096);                    // NDOM
    float* h      = (float*)(ws + 263168);                  // [MC][256] f32
    u16*   ybf    = (u16*)(ws + 34079744);                  // [MC][256] bf16
    u16*   qkvc   = (u16*)(ws + 50988032);                  // [MC][768] bf16
    u16*   ffb    = (u16*)(ws + 101712896);                 // [MC][1024] bf16
    u16*   wq     = (u16*)(ws + 169346048);                 // 4 x [768][256]
    u16*   wo     = (u16*)(ws + 170918912);                 // 4 x [256][256]
    u16*   w1     = (u16*)(ws + 171443200);                 // 4 x [1024][256]
    u16*   w2     = (u16*)(ws + 173540352);                 // 4 x [256][1024]
    u16*   wpj    = (u16*)(ws + 175637504);                 // [256][128]
    u16*   embbf  = qkvc;                                   // alias (pre-loop only)

    k_zero_counts<<<1, 64, 0, stream>>>(counts);
    k_pos<<<NDOM / 256, 256, 0, stream>>>(idx, counts, pos);
    k_base<<<1, 64, 0, stream>>>(counts, base);
    k_rmap<<<NDOM / 256, 256, 0, stream>>>(idx, pos, base, rmap);
    k_b16<<<(NDOM * DIN / 4) / 256, 256, 0, stream>>>(emb, embbf, NDOM * DIN / 4);
    k_wt_all<<<776, 256, 0, stream>>>(projw, qkvw, outw, ff1w, ff2w,
                                      wpj, wq, wo, w1, w2);
    k_init_cls<<<BATCH, 256, 0, stream>>>(base, cls, h);
    k_gemm_bf<0,0,1,1><<<dim3(2, 256), 256, 0, stream>>>(
        embbf, wpj, projb, h, nullptr, rmap, DIN, DMODEL);
    k_ln_bf<<<MC / 4, 256, 0, stream>>>(h, ln1g, ln1b, ybf);

    for (int l = 0; l < NLAYER; ++l) {
        k_gemm_bf<0,1,0,0><<<dim3(6, MTILES), 256, 0, stream>>>(
            ybf, wq + (size_t)l * 196608, qkvb + l * 768, nullptr, qkvc, nullptr, 256, 768);
        k_attn_mfma<<<1536, 512, 0, stream>>>(qkvc, counts, base, ybf);
        k_gemm_ln<1><<<MTILES, 512, 0, stream>>>(
            ybf, wo + (size_t)l * 65536, outb + l * DMODEL, h, ybf,
            ln2g + l * DMODEL, ln2b + l * DMODEL, 256);
        k_gemm_bf<1,1,0,0><<<dim3(8, MTILES), 256, 0, stream>>>(
            ybf, w1 + (size_t)l * 262144, ff1b + l * DFFN, nullptr, ffb, nullptr, 256, 1024);
        if (l < NLAYER - 1)
            k_gemm_ln<1><<<MTILES, 512, 0, stream>>>(
                ffb, w2 + (size_t)l * 262144, ff2b + l * DMODEL, h, ybf,
                ln1g + (l + 1) * DMODEL, ln1b + (l + 1) * DMODEL, 1024);
        else
            k_gemm_ln<0><<<MTILES, 512, 0, stream>>>(
                ffb, w2 + (size_t)l * 262144, ff2b + l * DMODEL, h, nullptr,
                nullptr, nullptr, 1024);
    }

    k_head<<<BATCH, 256, 0, stream>>>(h, base, h1w, h1b, h2w, h2b, out);
}

// Round 9
// 1076.854 us; speedup vs baseline: 1.0993x; 1.0084x over previous
//
#include <hip/hip_runtime.h>
#include <cstdint>
#include <cstddef>

#define NDOM   32768
#define DIN    128
#define DMODEL 256
#define NHEAD  4
#define NLAYER 4
#define DFFN   1024
#define BATCH  64
#define SEQ    672
#define DHEAD  64
#define MC     33024   // compact rows padded: 32832 live (NDOM+BATCH) + scratch tail
#define MTILES 258     // MC/128

typedef unsigned short u16;
typedef __attribute__((ext_vector_type(8))) short bf8;   // 8 bf16 (4 VGPRs)
typedef __attribute__((ext_vector_type(4))) float f4;    // MFMA accumulator

__device__ inline u16 f2b(float x) {            // f32 -> bf16 RNE
    union { float f; unsigned u; } c; c.f = x;
    unsigned r = c.u + 0x7fffu + ((c.u >> 16) & 1u);
    return (u16)(r >> 16);
}

__device__ inline void gload16(const void* g, const void* l) {
    __builtin_amdgcn_global_load_lds(
        (const __attribute__((address_space(1))) void*)g,
        (__attribute__((address_space(3))) void*)l, 16, 0, 0);
}

// ---------------- setup ----------------

__global__ void k_zero_counts(int* __restrict__ counts) {
    if (threadIdx.x < BATCH) counts[threadIdx.x] = 0;
}

__global__ void k_pos(const int* __restrict__ idx, int* __restrict__ counts,
                      int* __restrict__ pos) {
    int i = blockIdx.x * blockDim.x + threadIdx.x;
    if (i < NDOM) pos[i] = atomicAdd(&counts[idx[i]], 1);
}

// segment bases via wave prefix-sum: base[b] = b + sum_{j<b} counts[j]
__global__ void k_base(const int* __restrict__ counts, int* __restrict__ base) {
    const int lane = threadIdx.x;
    const int c = counts[lane];
    int s = c;
    #pragma unroll
    for (int off = 1; off < 64; off <<= 1) {
        int t = __shfl_up(s, off);
        if (lane >= off) s += t;
    }
    base[lane] = lane + (s - c);
    if (lane == 63) base[64] = 64 + s;
}

// rmap[i] = compact row of dom i
__global__ void k_rmap(const int* __restrict__ idx, const int* __restrict__ pos,
                       const int* __restrict__ base, int* __restrict__ rmap) {
    int i = blockIdx.x * 256 + threadIdx.x;
    if (i < NDOM) {
        int p = pos[i] + 1;
        rmap[i] = (p < SEQ) ? base[idx[i]] + p : (MC - 1);  // overflow -> scratch row
    }
}

__global__ void k_init_cls(const int* __restrict__ base, const float* __restrict__ cls,
                           float* __restrict__ h) {
    h[(size_t)base[blockIdx.x] * DMODEL + threadIdx.x] = cls[threadIdx.x];
}

// f32 -> bf16 bulk convert (vectorized)
__global__ void k_b16(const float* __restrict__ x, u16* __restrict__ y, int n4) {
    int i = blockIdx.x * 256 + threadIdx.x;
    if (i < n4) {
        float4 v = ((const float4*)x)[i];
        ushort4 o;
        o.x = f2b(v.x); o.y = f2b(v.y); o.z = f2b(v.z); o.w = f2b(v.w);
        ((ushort4*)y)[i] = o;
    }
}

// merged weight convert+transpose, one 64x64 tile per block, LDS-coalesced.
__global__ __launch_bounds__(256) void k_wt_all(
    const float* __restrict__ projw, const float* __restrict__ qkvw,
    const float* __restrict__ outw,  const float* __restrict__ ff1w,
    const float* __restrict__ ff2w,
    u16* __restrict__ wpj, u16* __restrict__ wq, u16* __restrict__ wo,
    u16* __restrict__ w1,  u16* __restrict__ w2)
{
    __shared__ float t[64][65];
    const int tile = blockIdx.x;
    const float* W; u16* D; int K, N, local;
    if (tile < 8)        { W = projw; D = wpj; K = 128;  N = 256;  local = tile; }
    else if (tile < 200) { int l = (tile-8)/48;   local = (tile-8)%48;
                           W = qkvw + (size_t)l*196608; D = wq + (size_t)l*196608; K = 256;  N = 768; }
    else if (tile < 264) { int l = (tile-200)/16; local = (tile-200)%16;
                           W = outw + (size_t)l*65536;  D = wo + (size_t)l*65536;  K = 256;  N = 256; }
    else if (tile < 520) { int l = (tile-264)/64; local = (tile-264)%64;
                           W = ff1w + (size_t)l*262144; D = w1 + (size_t)l*262144; K = 256;  N = 1024; }
    else                 { int l = (tile-520)/64; local = (tile-520)%64;
                           W = ff2w + (size_t)l*262144; D = w2 + (size_t)l*262144; K = 1024; N = 256; }
    const int ntn = N >> 6;
    const int tk = local / ntn, tn = local % ntn;
    const int r = threadIdx.x >> 6, c = threadIdx.x & 63;
    #pragma unroll 4
    for (int rr = r; rr < 64; rr += 4)
        t[rr][c] = W[(size_t)(tk*64 + rr) * N + tn*64 + c];
    __syncthreads();
    #pragma unroll 4
    for (int rr = r; rr < 64; rr += 4)
        D[(size_t)(tn*64 + rr) * K + tk*64 + c] = f2b(t[c][rr]);
}

// ---------------- layernorm -> bf16 (layer-0 ln1 only) ----------------

__global__ __launch_bounds__(256) void k_ln_bf(
    const float* __restrict__ x, const float* __restrict__ g,
    const float* __restrict__ bt, u16* __restrict__ y)
{
    const int row  = blockIdx.x * 4 + (threadIdx.x >> 6);
    const int lane = threadIdx.x & 63;
    float4 v = ((const float4*)(x + (size_t)row * DMODEL))[lane];
    float s = v.x + v.y + v.z + v.w;
    #pragma unroll
    for (int off = 32; off >= 1; off >>= 1) s += __shfl_xor(s, off);
    const float m = s * (1.f / DMODEL);
    const float d0 = v.x - m, d1 = v.y - m, d2 = v.z - m, d3 = v.w - m;
    float q = d0*d0 + d1*d1 + d2*d2 + d3*d3;
    #pragma unroll
    for (int off = 32; off >= 1; off >>= 1) q += __shfl_xor(q, off);
    const float rstd = rsqrtf(q * (1.f / DMODEL) + 1e-5f);
    const float4 gv = ((const float4*)g)[lane];
    const float4 bv = ((const float4*)bt)[lane];
    ushort4 o;
    o.x = f2b(d0 * rstd * gv.x + bv.x);
    o.y = f2b(d1 * rstd * gv.y + bv.y);
    o.z = f2b(d2 * rstd * gv.z + bv.z);
    o.w = f2b(d3 * rstd * gv.w + bv.w);
    ((ushort4*)(y + (size_t)row * DMODEL))[lane] = o;
}

// ---------------- bf16 MFMA GEMM (128x128, 4 waves): qkv / ff1 / proj ----------------

template<int RELU, int OBF, int OF32, int SCAT>
__global__ __launch_bounds__(256) void k_gemm_bf(
    const u16* __restrict__ A, const u16* __restrict__ Bt,
    const float* __restrict__ bias, float* __restrict__ Cf,
    u16* __restrict__ Cb, const int* __restrict__ rmap, int K, int N)
{
    __shared__ u16 As[8192];   // [128][64] bf16, swizzled
    __shared__ u16 Bs[8192];
    const int tid = threadIdx.x;
    const int w = tid >> 6, lane = tid & 63;
    const int lr = lane & 15, lg = lane >> 4;
    const int m0 = blockIdx.y * 128, n0 = blockIdx.x * 128;
    const int wm = (w >> 1) * 64, wn = (w & 1) * 64;

    const f4 zf = {0.f, 0.f, 0.f, 0.f};
    f4 acc[4][4];
    #pragma unroll
    for (int i = 0; i < 4; ++i)
        #pragma unroll
        for (int j = 0; j < 4; ++j) acc[i][j] = zf;

    const int srow8 = lane >> 3;
    const int sq = lane & 7;

    for (int k0 = 0; k0 < K; k0 += 64) {
        #pragma unroll
        for (int c = 0; c < 4; ++c) {
            const int chunk = w * 4 + c;
            const int row = chunk * 8 + srow8;
            const int ks = k0 + ((sq ^ (row & 7)) << 3);
            gload16(A  + (size_t)(m0 + row) * K + ks, (const char*)As + chunk * 1024);
            gload16(Bt + (size_t)(n0 + row) * K + ks, (const char*)Bs + chunk * 1024);
        }
        __syncthreads();
        #pragma unroll
        for (int kk = 0; kk < 2; ++kk) {
            bf8 af[4], bg[4];
            #pragma unroll
            for (int f = 0; f < 4; ++f) {
                const int ra = wm + f * 16 + lr;
                af[f] = *(const bf8*)((const char*)As + ra * 128 +
                        ((((kk << 2) | lg) ^ (ra & 7)) << 4));
                const int rb = wn + f * 16 + lr;
                bg[f] = *(const bf8*)((const char*)Bs + rb * 128 +
                        ((((kk << 2) | lg) ^ (rb & 7)) << 4));
            }
            #pragma unroll
            for (int fm = 0; fm < 4; ++fm)
                #pragma unroll
                for (int fn = 0; fn < 4; ++fn)
                    acc[fm][fn] = __builtin_amdgcn_mfma_f32_16x16x32_bf16(
                        af[fm], bg[fn], acc[fm][fn], 0, 0, 0);
        }
        __syncthreads();
    }

    float bv[4];
    #pragma unroll
    for (int fn = 0; fn < 4; ++fn) bv[fn] = bias[n0 + wn + fn * 16 + lr];
    #pragma unroll
    for (int fm = 0; fm < 4; ++fm)
        #pragma unroll
        for (int j = 0; j < 4; ++j) {
            const int row = m0 + wm + fm * 16 + lg * 4 + j;
            const int orow = SCAT ? rmap[row] : row;
            #pragma unroll
            for (int fn = 0; fn < 4; ++fn) {
                float v = acc[fm][fn][j] + bv[fn];
                if (RELU) v = fmaxf(v, 0.f);
                const size_t off = (size_t)orow * N + n0 + wn + fn * 16 + lr;
                if (OF32)  Cf[off] = v;
                if (OBF)   Cb[off] = f2b(v);
            }
        }
}

// ---------------- fused GEMM(+resid)+LN: 64x256 tile, 4 waves, 2-phase dbuf ----------------
// h_new = h_old + A@Bt^T + bias; ybf = LN(h_new) (if LNF). N fixed = 256.
// Wave w owns rows w*16..w*16+15 (complete rows -> wave-local LN reduction).

template<int LNF>
__global__ __launch_bounds__(256) void k_gemm_ln(
    const u16* __restrict__ A, const u16* __restrict__ Bt,
    const float* __restrict__ bias, float* __restrict__ h,
    u16* __restrict__ ybf, const float* __restrict__ lng,
    const float* __restrict__ lnb, int K)
{
    __shared__ u16 AS[2][4096];    // [64][64] x2 (8KB each)
    __shared__ u16 BS[2][16384];   // [256][64] x2 (32KB each)
    const int tid = threadIdx.x;
    const int w = tid >> 6, lane = tid & 63;
    const int lr = lane & 15, lg = lane >> 4;
    const int m0 = blockIdx.x * 64;
    const int srow8 = lane >> 3, sq = lane & 7;

    const f4 zf = {0.f, 0.f, 0.f, 0.f};
    f4 acc[16];
    #pragma unroll
    for (int fn = 0; fn < 16; ++fn) acc[fn] = zf;

    const int NT = K >> 6;

    // prologue stage
    {
        #pragma unroll
        for (int c = 0; c < 2; ++c) {
            const int chunk = w * 2 + c;
            const int row = chunk * 8 + srow8;
            const int ks = (sq ^ (row & 7)) << 3;
            gload16(A + (size_t)(m0 + row) * K + ks, (const char*)AS[0] + chunk * 1024);
        }
        #pragma unroll
        for (int c = 0; c < 8; ++c) {
            const int chunk = w * 8 + c;
            const int row = chunk * 8 + srow8;
            const int ks = (sq ^ (row & 7)) << 3;
            gload16(Bt + (size_t)row * K + ks, (const char*)BS[0] + chunk * 1024);
        }
    }
    __syncthreads();

    int cur = 0;
    for (int t = 0; t < NT; ++t) {
        // issue next-tile stage into the other buffer (lands by next barrier)
        if (t + 1 < NT) {
            const int k0 = (t + 1) << 6;
            #pragma unroll
            for (int c = 0; c < 2; ++c) {
                const int chunk = w * 2 + c;
                const int row = chunk * 8 + srow8;
                const int ks = k0 + ((sq ^ (row & 7)) << 3);
                gload16(A + (size_t)(m0 + row) * K + ks, (const char*)AS[cur ^ 1] + chunk * 1024);
            }
            #pragma unroll
            for (int c = 0; c < 8; ++c) {
                const int chunk = w * 8 + c;
                const int row = chunk * 8 + srow8;
                const int ks = k0 + ((sq ^ (row & 7)) << 3);
                gload16(Bt + (size_t)row * K + ks, (const char*)BS[cur ^ 1] + chunk * 1024);
            }
        }
        // compute current buffer
        #pragma unroll
        for (int kk = 0; kk < 2; ++kk) {
            const int ra = w * 16 + lr;
            const bf8 af = *(const bf8*)((const char*)AS[cur] + ra * 128 +
                    ((((kk << 2) | lg) ^ (ra & 7)) << 4));
            #pragma unroll
            for (int fn = 0; fn < 16; ++fn) {
                const int rb = fn * 16 + lr;
                const bf8 bg = *(const bf8*)((const char*)BS[cur] + rb * 128 +
                        ((((kk << 2) | lg) ^ (rb & 7)) << 4));
                acc[fn] = __builtin_amdgcn_mfma_f32_16x16x32_bf16(af, bg, acc[fn], 0, 0, 0);
            }
        }
        __syncthreads();   // drains the in-flight stage (vmcnt 0) once per K-step
        cur ^= 1;
    }

    // epilogue: v = acc + bias + h_old; wave-local LN
    float bv[16], gl[16], bl[16];
    #pragma unroll
    for (int fn = 0; fn < 16; ++fn) {
        bv[fn] = bias[fn * 16 + lr];
        if (LNF) { gl[fn] = lng[fn * 16 + lr]; bl[fn] = lnb[fn * 16 + lr]; }
    }
    #pragma unroll
    for (int j = 0; j < 4; ++j) {
        const int row = m0 + w * 16 + lg * 4 + j;
        float s = 0.f, s2 = 0.f;
        #pragma unroll
        for (int fn = 0; fn < 16; ++fn) {
            float v = acc[fn][j] + bv[fn] + h[(size_t)row * DMODEL + fn * 16 + lr];
            acc[fn][j] = v;
            s += v; s2 += v * v;
        }
        if (LNF) {
            #pragma unroll
            for (int off = 1; off <= 8; off <<= 1) {
                s  += __shfl_xor(s, off);
                s2 += __shfl_xor(s2, off);
            }
            const float mean = s * (1.f / DMODEL);
            const float var  = s2 * (1.f / DMODEL) - mean * mean;
            const float rstd = rsqrtf(var + 1e-5f);
            #pragma unroll
            for (int fn = 0; fn < 16; ++fn) {
                const size_t off2 = (size_t)row * DMODEL + fn * 16 + lr;
                const float v = acc[fn][j];
                h[off2] = v;
                ybf[off2] = f2b((v - mean) * rstd * gl[fn] + bl[fn]);
            }
        } else {
            #pragma unroll
            for (int fn = 0; fn < 16; ++fn)
                h[(size_t)row * DMODEL + fn * 16 + lr] = acc[fn][j];
        }
    }
}

// ---------------- MFMA flash attention on compact segments ----------------
// Segment of batch b: rows base[b] .. base[b]+count[b] (row 0 = CLS).
// Keys valid iff 1 <= t <= count[b] (segment-relative). QBLK=128, 8 waves.

__global__ __launch_bounds__(512) void k_attn_mfma(
    const u16* __restrict__ qkv, const int* __restrict__ counts,
    const int* __restrict__ base, u16* __restrict__ out)
{
    __shared__ u16 Ks[4096];      // [64 key][64 dh] swizzled
    __shared__ u16 Vt[4096];      // [64 dh][64 key] swizzled
    __shared__ u16 Ps[8][1024];   // per-wave P [16 q][64 key] swizzled
    const int tid = threadIdx.x;
    const int w = tid >> 6, lane = tid & 63;
    const int lr = lane & 15, lg = lane >> 4;
    // XCD swizzle: 24 blocks (6 qt x 4 h) of one batch land on one XCD (L%8)
    const int L = blockIdx.x;
    const int b = (L & 7) * 8 + (L >> 3) / 24;
    const int r = (L >> 3) % 24;
    const int qt = r >> 2, hh = r & 3;
    const int q0 = qt * 128;
    const int kmax = min(counts[b], SEQ - 1);
    if (q0 > kmax) return;                   // dead query tile
    const int ntiles = (kmax + 64) >> 6;
    const size_t bb = (size_t)base[b];

    // Q fragments: q-row (segment) = q0 + w*16 + lr, dh = kk*32 + lg*8..+7
    const int qrow = q0 + w * 16 + lr;
    const size_t qoff = (bb + qrow) * 768 + hh * 64 + (lg << 3);
    const bf8 qf0 = *(const bf8*)(qkv + qoff);
    const bf8 qf1 = *(const bf8*)(qkv + qoff + 32);

    const f4 zf = {0.f, 0.f, 0.f, 0.f};
    f4 o_[4];
    #pragma unroll
    for (int fn = 0; fn < 4; ++fn) o_[fn] = zf;
    float mrow = -INFINITY, ssum = 0.f;

    for (int kt = 0; kt < ntiles; ++kt) {
        const int k0 = kt * 64;
        // stage K tile: 8 waves x 1 chunk (1KB)
        {
            const int row = w * 8 + (lane >> 3);
            const int q = lane & 7;
            gload16(qkv + (bb + k0 + row) * 768 + 256 + hh * 64 + ((q ^ (row & 7)) << 3),
                    (const char*)Ks + w * 1024);
        }
        // stage V transposed: 512 threads x (2 keys x 4 dh)
        {
            const int kk2 = (tid & 31) * 2;
            const int dh0 = (tid >> 5) * 4;
            const ushort4 v0 = *(const ushort4*)(qkv + (bb + k0 + kk2) * 768 + 512 + hh * 64 + dh0);
            const ushort4 v1 = *(const ushort4*)(qkv + (bb + k0 + kk2 + 1) * 768 + 512 + hh * 64 + dh0);
            const u16* pv0 = (const u16*)&v0;
            const u16* pv1 = (const u16*)&v1;
            #pragma unroll
            for (int e = 0; e < 4; ++e) {
                const int d = dh0 + e;
                const unsigned pk = (unsigned)pv0[e] | ((unsigned)pv1[e] << 16);
                *(unsigned*)((char*)Vt + d * 128 +
                    ((((kk2 >> 3) ^ (d & 7)) << 4)) + ((kk2 & 7) << 1)) = pk;
            }
        }
        __syncthreads();

        // QK^T swapped: lane holds S[q=lr][key = fk*16+lg*4+j]
        f4 sf[4];
        #pragma unroll
        for (int fk = 0; fk < 4; ++fk) sf[fk] = zf;
        #pragma unroll
        for (int kk = 0; kk < 2; ++kk) {
            const bf8 qf = kk ? qf1 : qf0;
            #pragma unroll
            for (int fk = 0; fk < 4; ++fk) {
                const int rk = fk * 16 + lr;
                const bf8 kf = *(const bf8*)((const char*)Ks + rk * 128 +
                        ((((kk << 2) | lg) ^ (rk & 7)) << 4));
                sf[fk] = __builtin_amdgcn_mfma_f32_16x16x32_bf16(kf, qf, sf[fk], 0, 0, 0);
            }
        }

        // online softmax (stats per q-row lr, replicated across 4 lane-groups)
        float sv[4][4];
        float pmax = -INFINITY;
        if (k0 >= 1 && k0 + 63 <= kmax) {            // interior tile: no masking
            #pragma unroll
            for (int fk = 0; fk < 4; ++fk)
                #pragma unroll
                for (int j = 0; j < 4; ++j) {
                    const float x = sf[fk][j] * 0.125f;
                    sv[fk][j] = x;
                    pmax = fmaxf(pmax, x);
                }
        } else {
            #pragma unroll
            for (int fk = 0; fk < 4; ++fk)
                #pragma unroll
                for (int j = 0; j < 4; ++j) {
                    const int key = k0 + fk * 16 + lg * 4 + j;
                    const float x = (key >= 1 && key <= kmax) ? sf[fk][j] * 0.125f : -INFINITY;
                    sv[fk][j] = x;
                    pmax = fmaxf(pmax, x);
                }
        }
        pmax = fmaxf(pmax, __shfl_xor(pmax, 16));
        pmax = fmaxf(pmax, __shfl_xor(pmax, 32));

        // defer-max (T13): only rescale when the running max grew by > 8
        if (!__all(pmax <= mrow + 8.f)) {
            const float mnew = fmaxf(mrow, pmax);
            const float fac = __expf(mrow - mnew);   // 0 on first tile
            mrow = mnew;
            ssum *= fac;
            #pragma unroll
            for (int j = 0; j < 4; ++j) {
                const float fj = __shfl(fac, lg * 4 + j);
                #pragma unroll
                for (int fn = 0; fn < 4; ++fn) o_[fn][j] *= fj;
            }
        }

        float tsum = 0.f;
        #pragma unroll
        for (int fk = 0; fk < 4; ++fk) {
            const float p0 = __expf(sv[fk][0] - mrow);
            const float p1 = __expf(sv[fk][1] - mrow);
            const float p2 = __expf(sv[fk][2] - mrow);
            const float p3 = __expf(sv[fk][3] - mrow);
            tsum += p0 + p1 + p2 + p3;
            ushort4 pk;
            pk.x = f2b(p0); pk.y = f2b(p1); pk.z = f2b(p2); pk.w = f2b(p3);
            *(ushort4*)((char*)Ps[w] + lr * 128 +
                (((((fk << 1) | (lg >> 1)) ^ (lr & 7)) << 4)) + ((lg & 1) << 3)) = pk;
        }
        tsum += __shfl_xor(tsum, 16);
        tsum += __shfl_xor(tsum, 32);
        ssum += tsum;
        __syncthreads();   // P visible

        // PV
        #pragma unroll
        for (int kk = 0; kk < 2; ++kk) {
            const bf8 pa = *(const bf8*)((const char*)Ps[w] + lr * 128 +
                    ((((kk << 2) | lg) ^ (lr & 7)) << 4));
            #pragma unroll
            for (int fn = 0; fn < 4; ++fn) {
                const int rv = fn * 16 + lr;
                const bf8 vf = *(const bf8*)((const char*)Vt + rv * 128 +
                        ((((kk << 2) | lg) ^ (rv & 7)) << 4));
                o_[fn] = __builtin_amdgcn_mfma_f32_16x16x32_bf16(pa, vf, o_[fn], 0, 0, 0);
            }
        }
        __syncthreads();   // everyone done with Ks/Vt/Ps before next stage
    }

    const float inv = 1.f / ssum;
    #pragma unroll
    for (int j = 0; j < 4; ++j) {
        const float ij = __shfl(inv, lg * 4 + j);
        const int qr = q0 + w * 16 + lg * 4 + j;
        if (qr <= kmax) {   // live rows only (don't cross into next segment)
            #pragma unroll
            for (int fn = 0; fn < 4; ++fn)
                out[(bb + qr) * DMODEL + hh * 64 + fn * 16 + lr] = f2b(o_[fn][j] * ij);
        }
    }
}

// ---------------- head ----------------

__global__ __launch_bounds__(256) void k_head(
    const float* __restrict__ h, const int* __restrict__ base,
    const float* __restrict__ w1, const float* __restrict__ b1,
    const float* __restrict__ w2, const float* __restrict__ b2,
    float* __restrict__ out)
{
    __shared__ float cbuf[DMODEL];
    __shared__ float p1[DMODEL];
    __shared__ float p2[3];
    const int b = blockIdx.x, tid = threadIdx.x;
    cbuf[tid] = h[(size_t)base[b] * DMODEL + tid];
    __syncthreads();
    float acc = b1[tid];
    #pragma unroll 8
    for (int k = 0; k < DMODEL; ++k) acc = fmaf(cbuf[k], w1[k * DMODEL + tid], acc);
    p1[tid] = fmaxf(acc, 0.f);
    __syncthreads();
    if (tid < 3) {
        float a = b2[tid];
        for (int k = 0; k < DMODEL; ++k) a = fmaf(p1[k], w2[k * 3 + tid], a);
        p2[tid] = a;
    }
    __syncthreads();
    if (tid < 3) {
        float n2 = p2[0]*p2[0] + p2[1]*p2[1] + p2[2]*p2[2];
        out[b * 3 + tid] = p2[tid] * rsqrtf(n2);
    }
}

// ---------------- launch ----------------

extern "C" void kernel_launch(void* const* d_in, const int* in_sizes, int n_in,
                              void* d_out, int out_size, void* d_ws, size_t ws_size,
                              hipStream_t stream) {
    const float* emb   = (const float*)d_in[0];
    const int*   idx   = (const int*)d_in[1];
    const float* projw = (const float*)d_in[4];
    const float* projb = (const float*)d_in[5];
    const float* cls   = (const float*)d_in[6];
    const float* ln1g  = (const float*)d_in[7];
    const float* ln1b  = (const float*)d_in[8];
    const float* qkvw  = (const float*)d_in[9];
    const float* qkvb  = (const float*)d_in[10];
    const float* outw  = (const float*)d_in[11];
    const float* outb  = (const float*)d_in[12];
    const float* ln2g  = (const float*)d_in[13];
    const float* ln2b  = (const float*)d_in[14];
    const float* ff1w  = (const float*)d_in[15];
    const float* ff1b  = (const float*)d_in[16];
    const float* ff2w  = (const float*)d_in[17];
    const float* ff2b  = (const float*)d_in[18];
    const float* h1w   = (const float*)d_in[19];
    const float* h1b   = (const float*)d_in[20];
    const float* h2w   = (const float*)d_in[21];
    const float* h2b   = (const float*)d_in[22];
    float* out = (float*)d_out;

    char* ws = (char*)d_ws;
    int*   counts = (int*)ws;                               // @0
    int*   base   = (int*)(ws + 256);                       // 65 ints
    int*   pos    = (int*)(ws + 1024);                      // NDOM
    int*   rmap   = (int*)(ws + 132096);                    // NDOM
    float* h      = (float*)(ws + 263168);                  // [MC][256] f32
    u16*   ybf    = (u16*)(ws + 34079744);                  // [MC][256] bf16
    u16*   qkvc   = (u16*)(ws + 50988032);                  // [MC][768] bf16
    u16*   ffb    = (u16*)(ws + 101712896);                 // [MC][1024] bf16
    u16*   wq     = (u16*)(ws + 169346048);                 // 4 x [768][256]
    u16*   wo     = (u16*)(ws + 170918912);                 // 4 x [256][256]
    u16*   w1     = (u16*)(ws + 171443200);                 // 4 x [1024][256]
    u16*   w2     = (u16*)(ws + 173540352);                 // 4 x [256][1024]
    u16*   wpj    = (u16*)(ws + 175637504);                 // [256][128]
    u16*   embbf  = qkvc;                                   // alias (pre-loop only)

    k_zero_counts<<<1, 64, 0, stream>>>(counts);
    k_pos<<<NDOM / 256, 256, 0, stream>>>(idx, counts, pos);
    k_base<<<1, 64, 0, stream>>>(counts, base);
    k_rmap<<<NDOM / 256, 256, 0, stream>>>(idx, pos, base, rmap);
    k_b16<<<(NDOM * DIN / 4) / 256, 256, 0, stream>>>(emb, embbf, NDOM * DIN / 4);
    k_wt_all<<<776, 256, 0, stream>>>(projw, qkvw, outw, ff1w, ff2w,
                                      wpj, wq, wo, w1, w2);
    k_init_cls<<<BATCH, 256, 0, stream>>>(base, cls, h);
    k_gemm_bf<0,0,1,1><<<dim3(2, 256), 256, 0, stream>>>(
        embbf, wpj, projb, h, nullptr, rmap, DIN, DMODEL);
    k_ln_bf<<<MC / 4, 256, 0, stream>>>(h, ln1g, ln1b, ybf);

    for (int l = 0; l < NLAYER; ++l) {
        k_gemm_bf<0,1,0,0><<<dim3(6, MTILES), 256, 0, stream>>>(
            ybf, wq + (size_t)l * 196608, qkvb + l * 768, nullptr, qkvc, nullptr, 256, 768);
        k_attn_mfma<<<1536, 512, 0, stream>>>(qkvc, counts, base, ybf);
        k_gemm_ln<1><<<MC / 64, 256, 0, stream>>>(
            ybf, wo + (size_t)l * 65536, outb + l * DMODEL, h, ybf,
            ln2g + l * DMODEL, ln2b + l * DMODEL, 256);
        k_gemm_bf<1,1,0,0><<<dim3(8, MTILES), 256, 0, stream>>>(
            ybf, w1 + (size_t)l * 262144, ff1b + l * DFFN, nullptr, ffb, nullptr, 256, 1024);
        if (l < NLAYER - 1)
            k_gemm_ln<1><<<MC / 64, 256, 0, stream>>>(
                ffb, w2 + (size_t)l * 262144, ff2b + l * DMODEL, h, ybf,
                ln1g + (l + 1) * DMODEL, ln1b + (l + 1) * DMODEL, 1024);
        else
            k_gemm_ln<0><<<MC / 64, 256, 0, stream>>>(
                ffb, w2 + (size_t)l * 262144, ff2b + l * DMODEL, h, nullptr,
                nullptr, nullptr, 1024);
    }

    k_head<<<BATCH, 256, 0, stream>>>(h, base, h1w, h1b, h2w, h2b, out);
}

// Round 12
// 1049.257 us; speedup vs baseline: 1.1282x; 1.0263x over previous
//
#include <hip/hip_runtime.h>
#include <cstdint>
#include <cstddef>

#define NDOM   32768
#define DIN    128
#define DMODEL 256
#define NHEAD  4
#define NLAYER 4
#define DFFN   1024
#define BATCH  64
#define SEQ    672
#define DHEAD  64
#define MC     33024   // compact rows padded: 32832 live (NDOM+BATCH) + scratch tail
#define MTILES 258     // MC/128

typedef unsigned short u16;
typedef __attribute__((ext_vector_type(8))) short bf8;   // 8 bf16 (4 VGPRs)
typedef __attribute__((ext_vector_type(4))) float f4;    // MFMA accumulator

__device__ inline u16 f2b(float x) {            // f32 -> bf16 RNE
    union { float f; unsigned u; } c; c.f = x;
    unsigned r = c.u + 0x7fffu + ((c.u >> 16) & 1u);
    return (u16)(r >> 16);
}

__device__ inline void gload16(const void* g, const void* l) {
    __builtin_amdgcn_global_load_lds(
        (const __attribute__((address_space(1))) void*)g,
        (__attribute__((address_space(3))) void*)l, 16, 0, 0);
}

// ---------------- setup ----------------

__global__ void k_zero_counts(int* __restrict__ counts) {
    if (threadIdx.x < BATCH) counts[threadIdx.x] = 0;
}

__global__ void k_pos(const int* __restrict__ idx, int* __restrict__ counts,
                      int* __restrict__ pos) {
    int i = blockIdx.x * blockDim.x + threadIdx.x;
    if (i < NDOM) pos[i] = atomicAdd(&counts[idx[i]], 1);
}

// segment bases via wave prefix-sum: base[b] = b + sum_{j<b} counts[j]
__global__ void k_base(const int* __restrict__ counts, int* __restrict__ base) {
    const int lane = threadIdx.x;
    const int c = counts[lane];
    int s = c;
    #pragma unroll
    for (int off = 1; off < 64; off <<= 1) {
        int t = __shfl_up(s, off);
        if (lane >= off) s += t;
    }
    base[lane] = lane + (s - c);
    if (lane == 63) base[64] = 64 + s;
}

// rmap[i] = compact row of dom i
__global__ void k_rmap(const int* __restrict__ idx, const int* __restrict__ pos,
                       const int* __restrict__ base, int* __restrict__ rmap) {
    int i = blockIdx.x * 256 + threadIdx.x;
    if (i < NDOM) {
        int p = pos[i] + 1;
        rmap[i] = (p < SEQ) ? base[idx[i]] + p : (MC - 1);  // overflow -> scratch row
    }
}

__global__ void k_init_cls(const int* __restrict__ base, const float* __restrict__ cls,
                           float* __restrict__ h) {
    h[(size_t)base[blockIdx.x] * DMODEL + threadIdx.x] = cls[threadIdx.x];
}

// f32 -> bf16 bulk convert (vectorized)
__global__ void k_b16(const float* __restrict__ x, u16* __restrict__ y, int n4) {
    int i = blockIdx.x * 256 + threadIdx.x;
    if (i < n4) {
        float4 v = ((const float4*)x)[i];
        ushort4 o;
        o.x = f2b(v.x); o.y = f2b(v.y); o.z = f2b(v.z); o.w = f2b(v.w);
        ((ushort4*)y)[i] = o;
    }
}

// merged weight convert+transpose, one 64x64 tile per block, LDS-coalesced.
__global__ __launch_bounds__(256) void k_wt_all(
    const float* __restrict__ projw, const float* __restrict__ qkvw,
    const float* __restrict__ outw,  const float* __restrict__ ff1w,
    const float* __restrict__ ff2w,
    u16* __restrict__ wpj, u16* __restrict__ wq, u16* __restrict__ wo,
    u16* __restrict__ w1,  u16* __restrict__ w2)
{
    __shared__ float t[64][65];
    const int tile = blockIdx.x;
    const float* W; u16* D; int K, N, local;
    if (tile < 8)        { W = projw; D = wpj; K = 128;  N = 256;  local = tile; }
    else if (tile < 200) { int l = (tile-8)/48;   local = (tile-8)%48;
                           W = qkvw + (size_t)l*196608; D = wq + (size_t)l*196608; K = 256;  N = 768; }
    else if (tile < 264) { int l = (tile-200)/16; local = (tile-200)%16;
                           W = outw + (size_t)l*65536;  D = wo + (size_t)l*65536;  K = 256;  N = 256; }
    else if (tile < 520) { int l = (tile-264)/64; local = (tile-264)%64;
                           W = ff1w + (size_t)l*262144; D = w1 + (size_t)l*262144; K = 256;  N = 1024; }
    else                 { int l = (tile-520)/64; local = (tile-520)%64;
                           W = ff2w + (size_t)l*262144; D = w2 + (size_t)l*262144; K = 1024; N = 256; }
    const int ntn = N >> 6;
    const int tk = local / ntn, tn = local % ntn;
    const int r = threadIdx.x >> 6, c = threadIdx.x & 63;
    #pragma unroll 4
    for (int rr = r; rr < 64; rr += 4)
        t[rr][c] = W[(size_t)(tk*64 + rr) * N + tn*64 + c];
    __syncthreads();
    #pragma unroll 4
    for (int rr = r; rr < 64; rr += 4)
        D[(size_t)(tn*64 + rr) * K + tk*64 + c] = f2b(t[c][rr]);
}

// ---------------- layernorm -> bf16 (streaming) ----------------

__global__ __launch_bounds__(256) void k_ln_bf(
    const float* __restrict__ x, const float* __restrict__ g,
    const float* __restrict__ bt, u16* __restrict__ y)
{
    const int row  = blockIdx.x * 4 + (threadIdx.x >> 6);
    const int lane = threadIdx.x & 63;
    float4 v = ((const float4*)(x + (size_t)row * DMODEL))[lane];
    float s = v.x + v.y + v.z + v.w;
    #pragma unroll
    for (int off = 32; off >= 1; off >>= 1) s += __shfl_xor(s, off);
    const float m = s * (1.f / DMODEL);
    const float d0 = v.x - m, d1 = v.y - m, d2 = v.z - m, d3 = v.w - m;
    float q = d0*d0 + d1*d1 + d2*d2 + d3*d3;
    #pragma unroll
    for (int off = 32; off >= 1; off >>= 1) q += __shfl_xor(q, off);
    const float rstd = rsqrtf(q * (1.f / DMODEL) + 1e-5f);
    const float4 gv = ((const float4*)g)[lane];
    const float4 bv = ((const float4*)bt)[lane];
    ushort4 o;
    o.x = f2b(d0 * rstd * gv.x + bv.x);
    o.y = f2b(d1 * rstd * gv.y + bv.y);
    o.z = f2b(d2 * rstd * gv.z + bv.z);
    o.w = f2b(d3 * rstd * gv.w + bv.w);
    ((ushort4*)(y + (size_t)row * DMODEL))[lane] = o;
}

// ---------------- bf16 MFMA GEMM (128x128, 4 waves): all dense GEMMs ----------------

template<int RELU, int OBF, int OF32, int RESID, int SCAT>
__global__ __launch_bounds__(256) void k_gemm_bf(
    const u16* __restrict__ A, const u16* __restrict__ Bt,
    const float* __restrict__ bias, float* __restrict__ Cf,
    u16* __restrict__ Cb, const int* __restrict__ rmap, int K, int N)
{
    __shared__ u16 As[8192];   // [128][64] bf16, swizzled
    __shared__ u16 Bs[8192];
    const int tid = threadIdx.x;
    const int w = tid >> 6, lane = tid & 63;
    const int lr = lane & 15, lg = lane >> 4;
    const int m0 = blockIdx.y * 128, n0 = blockIdx.x * 128;
    const int wm = (w >> 1) * 64, wn = (w & 1) * 64;

    const f4 zf = {0.f, 0.f, 0.f, 0.f};
    f4 acc[4][4];
    #pragma unroll
    for (int i = 0; i < 4; ++i)
        #pragma unroll
        for (int j = 0; j < 4; ++j) acc[i][j] = zf;

    const int srow8 = lane >> 3;
    const int sq = lane & 7;

    for (int k0 = 0; k0 < K; k0 += 64) {
        #pragma unroll
        for (int c = 0; c < 4; ++c) {
            const int chunk = w * 4 + c;
            const int row = chunk * 8 + srow8;
            const int ks = k0 + ((sq ^ (row & 7)) << 3);
            gload16(A  + (size_t)(m0 + row) * K + ks, (const char*)As + chunk * 1024);
            gload16(Bt + (size_t)(n0 + row) * K + ks, (const char*)Bs + chunk * 1024);
        }
        __syncthreads();
        #pragma unroll
        for (int kk = 0; kk < 2; ++kk) {
            bf8 af[4], bg[4];
            #pragma unroll
            for (int f = 0; f < 4; ++f) {
                const int ra = wm + f * 16 + lr;
                af[f] = *(const bf8*)((const char*)As + ra * 128 +
                        ((((kk << 2) | lg) ^ (ra & 7)) << 4));
                const int rb = wn + f * 16 + lr;
                bg[f] = *(const bf8*)((const char*)Bs + rb * 128 +
                        ((((kk << 2) | lg) ^ (rb & 7)) << 4));
            }
            #pragma unroll
            for (int fm = 0; fm < 4; ++fm)
                #pragma unroll
                for (int fn = 0; fn < 4; ++fn)
                    acc[fm][fn] = __builtin_amdgcn_mfma_f32_16x16x32_bf16(
                        af[fm], bg[fn], acc[fm][fn], 0, 0, 0);
        }
        __syncthreads();
    }

    float bv[4];
    #pragma unroll
    for (int fn = 0; fn < 4; ++fn) bv[fn] = bias[n0 + wn + fn * 16 + lr];
    #pragma unroll
    for (int fm = 0; fm < 4; ++fm)
        #pragma unroll
        for (int j = 0; j < 4; ++j) {
            const int row = m0 + wm + fm * 16 + lg * 4 + j;
            const int orow = SCAT ? rmap[row] : row;
            #pragma unroll
            for (int fn = 0; fn < 4; ++fn) {
                float v = acc[fm][fn][j] + bv[fn];
                if (RELU) v = fmaxf(v, 0.f);
                const size_t off = (size_t)orow * N + n0 + wn + fn * 16 + lr;
                if (RESID) Cf[off] += v;
                if (OF32)  Cf[off] = v;
                if (OBF)   Cb[off] = f2b(v);
            }
        }
}

// ---------------- MFMA flash attention on compact segments ----------------
// Segment of batch b: rows base[b] .. base[b]+count[b] (row 0 = CLS).
// Keys valid iff 1 <= t <= count[b] (segment-relative). QBLK=128, 8 waves.

__global__ __launch_bounds__(512) void k_attn_mfma(
    const u16* __restrict__ qkv, const int* __restrict__ counts,
    const int* __restrict__ base, u16* __restrict__ out)
{
    __shared__ u16 Ks[4096];      // [64 key][64 dh] swizzled
    __shared__ u16 Vt[4096];      // [64 dh][64 key] swizzled
    __shared__ u16 Ps[8][1024];   // per-wave P [16 q][64 key] swizzled
    const int tid = threadIdx.x;
    const int w = tid >> 6, lane = tid & 63;
    const int lr = lane & 15, lg = lane >> 4;
    // XCD swizzle: 24 blocks (6 qt x 4 h) of one batch land on one XCD (L%8)
    const int L = blockIdx.x;
    const int b = (L & 7) * 8 + (L >> 3) / 24;
    const int r = (L >> 3) % 24;
    const int qt = r >> 2, hh = r & 3;
    const int q0 = qt * 128;
    const int kmax = min(counts[b], SEQ - 1);
    if (q0 > kmax) return;                   // dead query tile
    const int ntiles = (kmax + 64) >> 6;
    const size_t bb = (size_t)base[b];

    // Q fragments: q-row (segment) = q0 + w*16 + lr, dh = kk*32 + lg*8..+7
    const int qrow = q0 + w * 16 + lr;
    const size_t qoff = (bb + qrow) * 768 + hh * 64 + (lg << 3);
    const bf8 qf0 = *(const bf8*)(qkv + qoff);
    const bf8 qf1 = *(const bf8*)(qkv + qoff + 32);

    const f4 zf = {0.f, 0.f, 0.f, 0.f};
    f4 o_[4];
    #pragma unroll
    for (int fn = 0; fn < 4; ++fn) o_[fn] = zf;
    float mrow = -INFINITY, ssum = 0.f;

    for (int kt = 0; kt < ntiles; ++kt) {
        const int k0 = kt * 64;
        // stage K tile: 8 waves x 1 chunk (1KB)
        {
            const int row = w * 8 + (lane >> 3);
            const int q = lane & 7;
            gload16(qkv + (bb + k0 + row) * 768 + 256 + hh * 64 + ((q ^ (row & 7)) << 3),
                    (const char*)Ks + w * 1024);
        }
        // stage V transposed: 512 threads x (2 keys x 4 dh)
        {
            const int kk2 = (tid & 31) * 2;
            const int dh0 = (tid >> 5) * 4;
            const ushort4 v0 = *(const ushort4*)(qkv + (bb + k0 + kk2) * 768 + 512 + hh * 64 + dh0);
            const ushort4 v1 = *(const ushort4*)(qkv + (bb + k0 + kk2 + 1) * 768 + 512 + hh * 64 + dh0);
            const u16* pv0 = (const u16*)&v0;
            const u16* pv1 = (const u16*)&v1;
            #pragma unroll
            for (int e = 0; e < 4; ++e) {
                const int d = dh0 + e;
                const unsigned pk = (unsigned)pv0[e] | ((unsigned)pv1[e] << 16);
                *(unsigned*)((char*)Vt + d * 128 +
                    ((((kk2 >> 3) ^ (d & 7)) << 4)) + ((kk2 & 7) << 1)) = pk;
            }
        }
        __syncthreads();

        // QK^T swapped: lane holds S[q=lr][key = fk*16+lg*4+j]
        f4 sf[4];
        #pragma unroll
        for (int fk = 0; fk < 4; ++fk) sf[fk] = zf;
        #pragma unroll
        for (int kk = 0; kk < 2; ++kk) {
            const bf8 qf = kk ? qf1 : qf0;
            #pragma unroll
            for (int fk = 0; fk < 4; ++fk) {
                const int rk = fk * 16 + lr;
                const bf8 kf = *(const bf8*)((const char*)Ks + rk * 128 +
                        ((((kk << 2) | lg) ^ (rk & 7)) << 4));
                sf[fk] = __builtin_amdgcn_mfma_f32_16x16x32_bf16(kf, qf, sf[fk], 0, 0, 0);
            }
        }

        // online softmax (stats per q-row lr, replicated across 4 lane-groups)
        float sv[4][4];
        float pmax = -INFINITY;
        if (k0 >= 1 && k0 + 63 <= kmax) {            // interior tile: no masking
            #pragma unroll
            for (int fk = 0; fk < 4; ++fk)
                #pragma unroll
                for (int j = 0; j < 4; ++j) {
                    const float x = sf[fk][j] * 0.125f;
                    sv[fk][j] = x;
                    pmax = fmaxf(pmax, x);
                }
        } else {
            #pragma unroll
            for (int fk = 0; fk < 4; ++fk)
                #pragma unroll
                for (int j = 0; j < 4; ++j) {
                    const int key = k0 + fk * 16 + lg * 4 + j;
                    const float x = (key >= 1 && key <= kmax) ? sf[fk][j] * 0.125f : -INFINITY;
                    sv[fk][j] = x;
                    pmax = fmaxf(pmax, x);
                }
        }
        pmax = fmaxf(pmax, __shfl_xor(pmax, 16));
        pmax = fmaxf(pmax, __shfl_xor(pmax, 32));

        // defer-max (T13): only rescale when the running max grew by > 8
        if (!__all(pmax <= mrow + 8.f)) {
            const float mnew = fmaxf(mrow, pmax);
            const float fac = __expf(mrow - mnew);   // 0 on first tile
            mrow = mnew;
            ssum *= fac;
            #pragma unroll
            for (int j = 0; j < 4; ++j) {
                const float fj = __shfl(fac, lg * 4 + j);
                #pragma unroll
                for (int fn = 0; fn < 4; ++fn) o_[fn][j] *= fj;
            }
        }

        float tsum = 0.f;
        #pragma unroll
        for (int fk = 0; fk < 4; ++fk) {
            const float p0 = __expf(sv[fk][0] - mrow);
            const float p1 = __expf(sv[fk][1] - mrow);
            const float p2 = __expf(sv[fk][2] - mrow);
            const float p3 = __expf(sv[fk][3] - mrow);
            tsum += p0 + p1 + p2 + p3;
            ushort4 pk;
            pk.x = f2b(p0); pk.y = f2b(p1); pk.z = f2b(p2); pk.w = f2b(p3);
            *(ushort4*)((char*)Ps[w] + lr * 128 +
                (((((fk << 1) | (lg >> 1)) ^ (lr & 7)) << 4)) + ((lg & 1) << 3)) = pk;
        }
        tsum += __shfl_xor(tsum, 16);
        tsum += __shfl_xor(tsum, 32);
        ssum += tsum;
        __syncthreads();   // P visible

        // PV
        #pragma unroll
        for (int kk = 0; kk < 2; ++kk) {
            const bf8 pa = *(const bf8*)((const char*)Ps[w] + lr * 128 +
                    ((((kk << 2) | lg) ^ (lr & 7)) << 4));
            #pragma unroll
            for (int fn = 0; fn < 4; ++fn) {
                const int rv = fn * 16 + lr;
                const bf8 vf = *(const bf8*)((const char*)Vt + rv * 128 +
                        ((((kk << 2) | lg) ^ (rv & 7)) << 4));
                o_[fn] = __builtin_amdgcn_mfma_f32_16x16x32_bf16(pa, vf, o_[fn], 0, 0, 0);
            }
        }
        __syncthreads();   // everyone done with Ks/Vt/Ps before next stage
    }

    const float inv = 1.f / ssum;
    #pragma unroll
    for (int j = 0; j < 4; ++j) {
        const float ij = __shfl(inv, lg * 4 + j);
        const int qr = q0 + w * 16 + lg * 4 + j;
        if (qr <= kmax) {   // live rows only (don't cross into next segment)
            #pragma unroll
            for (int fn = 0; fn < 4; ++fn)
                out[(bb + qr) * DMODEL + hh * 64 + fn * 16 + lr] = f2b(o_[fn][j] * ij);
        }
    }
}

// ---------------- head ----------------

__global__ __launch_bounds__(256) void k_head(
    const float* __restrict__ h, const int* __restrict__ base,
    const float* __restrict__ w1, const float* __restrict__ b1,
    const float* __restrict__ w2, const float* __restrict__ b2,
    float* __restrict__ out)
{
    __shared__ float cbuf[DMODEL];
    __shared__ float p1[DMODEL];
    __shared__ float p2[3];
    const int b = blockIdx.x, tid = threadIdx.x;
    cbuf[tid] = h[(size_t)base[b] * DMODEL + tid];
    __syncthreads();
    float acc = b1[tid];
    #pragma unroll 8
    for (int k = 0; k < DMODEL; ++k) acc = fmaf(cbuf[k], w1[k * DMODEL + tid], acc);
    p1[tid] = fmaxf(acc, 0.f);
    __syncthreads();
    if (tid < 3) {
        float a = b2[tid];
        for (int k = 0; k < DMODEL; ++k) a = fmaf(p1[k], w2[k * 3 + tid], a);
        p2[tid] = a;
    }
    __syncthreads();
    if (tid < 3) {
        float n2 = p2[0]*p2[0] + p2[1]*p2[1] + p2[2]*p2[2];
        out[b * 3 + tid] = p2[tid] * rsqrtf(n2);
    }
}

// ---------------- launch ----------------

extern "C" void kernel_launch(void* const* d_in, const int* in_sizes, int n_in,
                              void* d_out, int out_size, void* d_ws, size_t ws_size,
                              hipStream_t stream) {
    const float* emb   = (const float*)d_in[0];
    const int*   idx   = (const int*)d_in[1];
    const float* projw = (const float*)d_in[4];
    const float* projb = (const float*)d_in[5];
    const float* cls   = (const float*)d_in[6];
    const float* ln1g  = (const float*)d_in[7];
    const float* ln1b  = (const float*)d_in[8];
    const float* qkvw  = (const float*)d_in[9];
    const float* qkvb  = (const float*)d_in[10];
    const float* outw  = (const float*)d_in[11];
    const float* outb  = (const float*)d_in[12];
    const float* ln2g  = (const float*)d_in[13];
    const float* ln2b  = (const float*)d_in[14];
    const float* ff1w  = (const float*)d_in[15];
    const float* ff1b  = (const float*)d_in[16];
    const float* ff2w  = (const float*)d_in[17];
    const float* ff2b  = (const float*)d_in[18];
    const float* h1w   = (const float*)d_in[19];
    const float* h1b   = (const float*)d_in[20];
    const float* h2w   = (const float*)d_in[21];
    const float* h2b   = (const float*)d_in[22];
    float* out = (float*)d_out;

    char* ws = (char*)d_ws;
    int*   counts = (int*)ws;                               // @0
    int*   base   = (int*)(ws + 256);                       // 65 ints
    int*   pos    = (int*)(ws + 1024);                      // NDOM
    int*   rmap   = (int*)(ws + 132096);                    // NDOM
    float* h      = (float*)(ws + 263168);                  // [MC][256] f32
    u16*   ybf    = (u16*)(ws + 34079744);                  // [MC][256] bf16
    u16*   qkvc   = (u16*)(ws + 50988032);                  // [MC][768] bf16
    u16*   ffb    = (u16*)(ws + 101712896);                 // [MC][1024] bf16
    u16*   wq     = (u16*)(ws + 169346048);                 // 4 x [768][256]
    u16*   wo     = (u16*)(ws + 170918912);                 // 4 x [256][256]
    u16*   w1     = (u16*)(ws + 171443200);                 // 4 x [1024][256]
    u16*   w2     = (u16*)(ws + 173540352);                 // 4 x [256][1024]
    u16*   wpj    = (u16*)(ws + 175637504);                 // [256][128]
    u16*   embbf  = qkvc;                                   // alias (pre-loop only)

    k_zero_counts<<<1, 64, 0, stream>>>(counts);
    k_pos<<<NDOM / 256, 256, 0, stream>>>(idx, counts, pos);
    k_base<<<1, 64, 0, stream>>>(counts, base);
    k_rmap<<<NDOM / 256, 256, 0, stream>>>(idx, pos, base, rmap);
    k_b16<<<(NDOM * DIN / 4) / 256, 256, 0, stream>>>(emb, embbf, NDOM * DIN / 4);
    k_wt_all<<<776, 256, 0, stream>>>(projw, qkvw, outw, ff1w, ff2w,
                                      wpj, wq, wo, w1, w2);
    k_init_cls<<<BATCH, 256, 0, stream>>>(base, cls, h);
    k_gemm_bf<0,0,1,0,1><<<dim3(2, 256), 256, 0, stream>>>(
        embbf, wpj, projb, h, nullptr, rmap, DIN, DMODEL);
    k_ln_bf<<<MC / 4, 256, 0, stream>>>(h, ln1g, ln1b, ybf);

    for (int l = 0; l < NLAYER; ++l) {
        // qkv projection
        k_gemm_bf<0,1,0,0,0><<<dim3(6, MTILES), 256, 0, stream>>>(
            ybf, wq + (size_t)l * 196608, qkvb + l * 768, nullptr, qkvc, nullptr, 256, 768);
        // attention
        k_attn_mfma<<<1536, 512, 0, stream>>>(qkvc, counts, base, ybf);
        // out-proj + residual (RMW h), then LN2 -> ybf
        k_gemm_bf<0,0,0,1,0><<<dim3(2, MTILES), 256, 0, stream>>>(
            ybf, wo + (size_t)l * 65536, outb + l * DMODEL, h, nullptr, nullptr, 256, 256);
        k_ln_bf<<<MC / 4, 256, 0, stream>>>(h, ln2g + l * DMODEL, ln2b + l * DMODEL, ybf);
        // ffn
        k_gemm_bf<1,1,0,0,0><<<dim3(8, MTILES), 256, 0, stream>>>(
            ybf, w1 + (size_t)l * 262144, ff1b + l * DFFN, nullptr, ffb, nullptr, 256, 1024);
        k_gemm_bf<0,0,0,1,0><<<dim3(2, MTILES), 256, 0, stream>>>(
            ffb, w2 + (size_t)l * 262144, ff2b + l * DMODEL, h, nullptr, nullptr, 1024, 256);
        if (l < NLAYER - 1)
            k_ln_bf<<<MC / 4, 256, 0, stream>>>(
                h, ln1g + (l + 1) * DMODEL, ln1b + (l + 1) * DMODEL, ybf);
    }

    k_head<<<BATCH, 256, 0, stream>>>(h, base, h1w, h1b, h2w, h2b, out);
}

// Round 13
// 1021.955 us; speedup vs baseline: 1.1584x; 1.0267x over previous
//
#include <hip/hip_runtime.h>
#include <cstdint>
#include <cstddef>

#define NDOM   32768
#define DIN    128
#define DMODEL 256
#define NHEAD  4
#define NLAYER 4
#define DFFN   1024
#define BATCH  64
#define SEQ    672
#define DHEAD  64
#define MC     33024   // compact rows padded: 32832 live (NDOM+BATCH) + scratch tail
#define MTILES 258     // MC/128

typedef unsigned short u16;
typedef __attribute__((ext_vector_type(8))) short bf8;   // 8 bf16 (4 VGPRs)
typedef __attribute__((ext_vector_type(4))) float f4;    // MFMA accumulator

__device__ inline u16 f2b(float x) {            // f32 -> bf16 RNE
    union { float f; unsigned u; } c; c.f = x;
    unsigned r = c.u + 0x7fffu + ((c.u >> 16) & 1u);
    return (u16)(r >> 16);
}

__device__ inline void gload16(const void* g, const void* l) {
    __builtin_amdgcn_global_load_lds(
        (const __attribute__((address_space(1))) void*)g,
        (__attribute__((address_space(3))) void*)l, 16, 0, 0);
}

// ---------------- setup ----------------

__global__ void k_zero_counts(int* __restrict__ counts) {
    if (threadIdx.x < BATCH) counts[threadIdx.x] = 0;
}

__global__ void k_pos(const int* __restrict__ idx, int* __restrict__ counts,
                      int* __restrict__ pos) {
    int i = blockIdx.x * blockDim.x + threadIdx.x;
    if (i < NDOM) pos[i] = atomicAdd(&counts[idx[i]], 1);
}

// segment bases via wave prefix-sum: base[b] = b + sum_{j<b} counts[j]
__global__ void k_base(const int* __restrict__ counts, int* __restrict__ base) {
    const int lane = threadIdx.x;
    const int c = counts[lane];
    int s = c;
    #pragma unroll
    for (int off = 1; off < 64; off <<= 1) {
        int t = __shfl_up(s, off);
        if (lane >= off) s += t;
    }
    base[lane] = lane + (s - c);
    if (lane == 63) base[64] = 64 + s;
}

// rmap[i] = compact row of dom i
__global__ void k_rmap(const int* __restrict__ idx, const int* __restrict__ pos,
                       const int* __restrict__ base, int* __restrict__ rmap) {
    int i = blockIdx.x * 256 + threadIdx.x;
    if (i < NDOM) {
        int p = pos[i] + 1;
        rmap[i] = (p < SEQ) ? base[idx[i]] + p : (MC - 1);  // overflow -> scratch row
    }
}

__global__ void k_init_cls(const int* __restrict__ base, const float* __restrict__ cls,
                           float* __restrict__ h) {
    h[(size_t)base[blockIdx.x] * DMODEL + threadIdx.x] = cls[threadIdx.x];
}

// f32 -> bf16 bulk convert (vectorized)
__global__ void k_b16(const float* __restrict__ x, u16* __restrict__ y, int n4) {
    int i = blockIdx.x * 256 + threadIdx.x;
    if (i < n4) {
        float4 v = ((const float4*)x)[i];
        ushort4 o;
        o.x = f2b(v.x); o.y = f2b(v.y); o.z = f2b(v.z); o.w = f2b(v.w);
        ((ushort4*)y)[i] = o;
    }
}

// merged weight convert+transpose, one 64x64 tile per block, LDS-coalesced.
__global__ __launch_bounds__(256) void k_wt_all(
    const float* __restrict__ projw, const float* __restrict__ qkvw,
    const float* __restrict__ outw,  const float* __restrict__ ff1w,
    const float* __restrict__ ff2w,
    u16* __restrict__ wpj, u16* __restrict__ wq, u16* __restrict__ wo,
    u16* __restrict__ w1,  u16* __restrict__ w2)
{
    __shared__ float t[64][65];
    const int tile = blockIdx.x;
    const float* W; u16* D; int K, N, local;
    if (tile < 8)        { W = projw; D = wpj; K = 128;  N = 256;  local = tile; }
    else if (tile < 200) { int l = (tile-8)/48;   local = (tile-8)%48;
                           W = qkvw + (size_t)l*196608; D = wq + (size_t)l*196608; K = 256;  N = 768; }
    else if (tile < 264) { int l = (tile-200)/16; local = (tile-200)%16;
                           W = outw + (size_t)l*65536;  D = wo + (size_t)l*65536;  K = 256;  N = 256; }
    else if (tile < 520) { int l = (tile-264)/64; local = (tile-264)%64;
                           W = ff1w + (size_t)l*262144; D = w1 + (size_t)l*262144; K = 256;  N = 1024; }
    else                 { int l = (tile-520)/64; local = (tile-520)%64;
                           W = ff2w + (size_t)l*262144; D = w2 + (size_t)l*262144; K = 1024; N = 256; }
    const int ntn = N >> 6;
    const int tk = local / ntn, tn = local % ntn;
    const int r = threadIdx.x >> 6, c = threadIdx.x & 63;
    #pragma unroll 4
    for (int rr = r; rr < 64; rr += 4)
        t[rr][c] = W[(size_t)(tk*64 + rr) * N + tn*64 + c];
    __syncthreads();
    #pragma unroll 4
    for (int rr = r; rr < 64; rr += 4)
        D[(size_t)(tn*64 + rr) * K + tk*64 + c] = f2b(t[c][rr]);
}

// ---------------- layernorm -> bf16 (streaming) ----------------

__global__ __launch_bounds__(256) void k_ln_bf(
    const float* __restrict__ x, const float* __restrict__ g,
    const float* __restrict__ bt, u16* __restrict__ y)
{
    const int row  = blockIdx.x * 4 + (threadIdx.x >> 6);
    const int lane = threadIdx.x & 63;
    float4 v = ((const float4*)(x + (size_t)row * DMODEL))[lane];
    float s = v.x + v.y + v.z + v.w;
    #pragma unroll
    for (int off = 32; off >= 1; off >>= 1) s += __shfl_xor(s, off);
    const float m = s * (1.f / DMODEL);
    const float d0 = v.x - m, d1 = v.y - m, d2 = v.z - m, d3 = v.w - m;
    float q = d0*d0 + d1*d1 + d2*d2 + d3*d3;
    #pragma unroll
    for (int off = 32; off >= 1; off >>= 1) q += __shfl_xor(q, off);
    const float rstd = rsqrtf(q * (1.f / DMODEL) + 1e-5f);
    const float4 gv = ((const float4*)g)[lane];
    const float4 bv = ((const float4*)bt)[lane];
    ushort4 o;
    o.x = f2b(d0 * rstd * gv.x + bv.x);
    o.y = f2b(d1 * rstd * gv.y + bv.y);
    o.z = f2b(d2 * rstd * gv.z + bv.z);
    o.w = f2b(d3 * rstd * gv.w + bv.w);
    ((ushort4*)(y + (size_t)row * DMODEL))[lane] = o;
}

// ---------------- bf16 MFMA GEMM (128x128, 4 waves): all dense GEMMs ----------------

template<int RELU, int OBF, int OF32, int RESID, int SCAT>
__global__ __launch_bounds__(256) void k_gemm_bf(
    const u16* __restrict__ A, const u16* __restrict__ Bt,
    const float* __restrict__ bias, float* __restrict__ Cf,
    u16* __restrict__ Cb, const int* __restrict__ rmap, int K, int N)
{
    __shared__ u16 As[8192];   // [128][64] bf16, swizzled
    __shared__ u16 Bs[8192];
    const int tid = threadIdx.x;
    const int w = tid >> 6, lane = tid & 63;
    const int lr = lane & 15, lg = lane >> 4;
    const int m0 = blockIdx.y * 128, n0 = blockIdx.x * 128;
    const int wm = (w >> 1) * 64, wn = (w & 1) * 64;

    const f4 zf = {0.f, 0.f, 0.f, 0.f};
    f4 acc[4][4];
    #pragma unroll
    for (int i = 0; i < 4; ++i)
        #pragma unroll
        for (int j = 0; j < 4; ++j) acc[i][j] = zf;

    const int srow8 = lane >> 3;
    const int sq = lane & 7;

    for (int k0 = 0; k0 < K; k0 += 64) {
        #pragma unroll
        for (int c = 0; c < 4; ++c) {
            const int chunk = w * 4 + c;
            const int row = chunk * 8 + srow8;
            const int ks = k0 + ((sq ^ (row & 7)) << 3);
            gload16(A  + (size_t)(m0 + row) * K + ks, (const char*)As + chunk * 1024);
            gload16(Bt + (size_t)(n0 + row) * K + ks, (const char*)Bs + chunk * 1024);
        }
        __syncthreads();
        #pragma unroll
        for (int kk = 0; kk < 2; ++kk) {
            bf8 af[4], bg[4];
            #pragma unroll
            for (int f = 0; f < 4; ++f) {
                const int ra = wm + f * 16 + lr;
                af[f] = *(const bf8*)((const char*)As + ra * 128 +
                        ((((kk << 2) | lg) ^ (ra & 7)) << 4));
                const int rb = wn + f * 16 + lr;
                bg[f] = *(const bf8*)((const char*)Bs + rb * 128 +
                        ((((kk << 2) | lg) ^ (rb & 7)) << 4));
            }
            #pragma unroll
            for (int fm = 0; fm < 4; ++fm)
                #pragma unroll
                for (int fn = 0; fn < 4; ++fn)
                    acc[fm][fn] = __builtin_amdgcn_mfma_f32_16x16x32_bf16(
                        af[fm], bg[fn], acc[fm][fn], 0, 0, 0);
        }
        __syncthreads();
    }

    float bv[4];
    #pragma unroll
    for (int fn = 0; fn < 4; ++fn) bv[fn] = bias[n0 + wn + fn * 16 + lr];
    #pragma unroll
    for (int fm = 0; fm < 4; ++fm)
        #pragma unroll
        for (int j = 0; j < 4; ++j) {
            const int row = m0 + wm + fm * 16 + lg * 4 + j;
            const int orow = SCAT ? rmap[row] : row;
            #pragma unroll
            for (int fn = 0; fn < 4; ++fn) {
                float v = acc[fm][fn][j] + bv[fn];
                if (RELU) v = fmaxf(v, 0.f);
                const size_t off = (size_t)orow * N + n0 + wn + fn * 16 + lr;
                if (RESID) Cf[off] += v;
                if (OF32)  Cf[off] = v;
                if (OBF)   Cb[off] = f2b(v);
            }
        }
}

// ---------------- MFMA flash attention on compact segments ----------------
// Segment of batch b: rows base[b] .. base[b]+count[b] (row 0 = CLS).
// Keys valid iff 1 <= t <= count[b] (segment-relative). QBLK=128, 8 waves.
// Double-buffered K/V staging, ONE barrier per k-tile (stage t+1 issued
// before compute t; Ps is wave-local so no mid-tile barrier needed).

__global__ __launch_bounds__(512) void k_attn_mfma(
    const u16* __restrict__ qkv, const int* __restrict__ counts,
    const int* __restrict__ base, u16* __restrict__ out)
{
    __shared__ u16 Ks[2][4096];   // [64 key][64 dh] swizzled, x2
    __shared__ u16 Vt[2][4096];   // [64 dh][64 key] swizzled, x2
    __shared__ u16 Ps[8][1024];   // per-wave P [16 q][64 key] swizzled
    const int tid = threadIdx.x;
    const int w = tid >> 6, lane = tid & 63;
    const int lr = lane & 15, lg = lane >> 4;
    // XCD swizzle: 24 blocks (6 qt x 4 h) of one batch land on one XCD (L%8)
    const int L = blockIdx.x;
    const int b = (L & 7) * 8 + (L >> 3) / 24;
    const int r = (L >> 3) % 24;
    const int qt = r >> 2, hh = r & 3;
    const int q0 = qt * 128;
    const int kmax = min(counts[b], SEQ - 1);
    if (q0 > kmax) return;                   // dead query tile
    const int ntiles = (kmax + 64) >> 6;
    const size_t bb = (size_t)base[b];

    // staging lane roles (constant per thread)
    const int krow8 = w * 8 + (lane >> 3);   // K stage: row within tile
    const int kq8 = lane & 7;                // K stage: 16B slot
    const int vkk2 = (tid & 31) * 2;         // V stage: key pair
    const int vdh0 = (tid >> 5) * 4;         // V stage: dh group

    // Q fragments: q-row (segment) = q0 + w*16 + lr, dh = kk*32 + lg*8..+7
    const int qrow = q0 + w * 16 + lr;
    const size_t qoff = (bb + qrow) * 768 + hh * 64 + (lg << 3);
    const bf8 qf0 = *(const bf8*)(qkv + qoff);
    const bf8 qf1 = *(const bf8*)(qkv + qoff + 32);

    const f4 zf = {0.f, 0.f, 0.f, 0.f};
    f4 o_[4];
    #pragma unroll
    for (int fn = 0; fn < 4; ++fn) o_[fn] = zf;
    float mrow = -INFINITY, ssum = 0.f;

    // prologue: stage tile 0 into buffer 0
    {
        gload16(qkv + (bb + krow8) * 768 + 256 + hh * 64 + ((kq8 ^ (krow8 & 7)) << 3),
                (const char*)Ks[0] + w * 1024);
        const ushort4 v0 = *(const ushort4*)(qkv + (bb + vkk2) * 768 + 512 + hh * 64 + vdh0);
        const ushort4 v1 = *(const ushort4*)(qkv + (bb + vkk2 + 1) * 768 + 512 + hh * 64 + vdh0);
        const u16* pv0 = (const u16*)&v0;
        const u16* pv1 = (const u16*)&v1;
        #pragma unroll
        for (int e = 0; e < 4; ++e) {
            const int d = vdh0 + e;
            const unsigned pk = (unsigned)pv0[e] | ((unsigned)pv1[e] << 16);
            *(unsigned*)((char*)Vt[0] + d * 128 +
                ((((vkk2 >> 3) ^ (d & 7)) << 4)) + ((vkk2 & 7) << 1)) = pk;
        }
    }
    __syncthreads();   // buffer 0 ready

    int cur = 0;
    for (int kt = 0; kt < ntiles; ++kt) {
        const int k0 = kt * 64;

        // issue stage of tile kt+1 into the other buffer (overlaps compute below)
        if (kt + 1 < ntiles) {
            const int kn = k0 + 64;
            gload16(qkv + (bb + kn + krow8) * 768 + 256 + hh * 64 + ((kq8 ^ (krow8 & 7)) << 3),
                    (const char*)Ks[cur ^ 1] + w * 1024);
            const ushort4 v0 = *(const ushort4*)(qkv + (bb + kn + vkk2) * 768 + 512 + hh * 64 + vdh0);
            const ushort4 v1 = *(const ushort4*)(qkv + (bb + kn + vkk2 + 1) * 768 + 512 + hh * 64 + vdh0);
            const u16* pv0 = (const u16*)&v0;
            const u16* pv1 = (const u16*)&v1;
            #pragma unroll
            for (int e = 0; e < 4; ++e) {
                const int d = vdh0 + e;
                const unsigned pk = (unsigned)pv0[e] | ((unsigned)pv1[e] << 16);
                *(unsigned*)((char*)Vt[cur ^ 1] + d * 128 +
                    ((((vkk2 >> 3) ^ (d & 7)) << 4)) + ((vkk2 & 7) << 1)) = pk;
            }
        }

        // QK^T swapped: lane holds S[q=lr][key = fk*16+lg*4+j]
        f4 sf[4];
        #pragma unroll
        for (int fk = 0; fk < 4; ++fk) sf[fk] = zf;
        #pragma unroll
        for (int kk = 0; kk < 2; ++kk) {
            const bf8 qf = kk ? qf1 : qf0;
            #pragma unroll
            for (int fk = 0; fk < 4; ++fk) {
                const int rk = fk * 16 + lr;
                const bf8 kf = *(const bf8*)((const char*)Ks[cur] + rk * 128 +
                        ((((kk << 2) | lg) ^ (rk & 7)) << 4));
                sf[fk] = __builtin_amdgcn_mfma_f32_16x16x32_bf16(kf, qf, sf[fk], 0, 0, 0);
            }
        }

        // online softmax (stats per q-row lr, replicated across 4 lane-groups)
        float sv[4][4];
        float pmax = -INFINITY;
        if (k0 >= 1 && k0 + 63 <= kmax) {            // interior tile: no masking
            #pragma unroll
            for (int fk = 0; fk < 4; ++fk)
                #pragma unroll
                for (int j = 0; j < 4; ++j) {
                    const float x = sf[fk][j] * 0.125f;
                    sv[fk][j] = x;
                    pmax = fmaxf(pmax, x);
                }
        } else {
            #pragma unroll
            for (int fk = 0; fk < 4; ++fk)
                #pragma unroll
                for (int j = 0; j < 4; ++j) {
                    const int key = k0 + fk * 16 + lg * 4 + j;
                    const float x = (key >= 1 && key <= kmax) ? sf[fk][j] * 0.125f : -INFINITY;
                    sv[fk][j] = x;
                    pmax = fmaxf(pmax, x);
                }
        }
        pmax = fmaxf(pmax, __shfl_xor(pmax, 16));
        pmax = fmaxf(pmax, __shfl_xor(pmax, 32));

        // defer-max (T13): only rescale when the running max grew by > 8
        if (!__all(pmax <= mrow + 8.f)) {
            const float mnew = fmaxf(mrow, pmax);
            const float fac = __expf(mrow - mnew);   // 0 on first tile
            mrow = mnew;
            ssum *= fac;
            #pragma unroll
            for (int j = 0; j < 4; ++j) {
                const float fj = __shfl(fac, lg * 4 + j);
                #pragma unroll
                for (int fn = 0; fn < 4; ++fn) o_[fn][j] *= fj;
            }
        }

        float tsum = 0.f;
        #pragma unroll
        for (int fk = 0; fk < 4; ++fk) {
            const float p0 = __expf(sv[fk][0] - mrow);
            const float p1 = __expf(sv[fk][1] - mrow);
            const float p2 = __expf(sv[fk][2] - mrow);
            const float p3 = __expf(sv[fk][3] - mrow);
            tsum += p0 + p1 + p2 + p3;
            ushort4 pk;
            pk.x = f2b(p0); pk.y = f2b(p1); pk.z = f2b(p2); pk.w = f2b(p3);
            *(ushort4*)((char*)Ps[w] + lr * 128 +
                (((((fk << 1) | (lg >> 1)) ^ (lr & 7)) << 4)) + ((lg & 1) << 3)) = pk;
        }
        tsum += __shfl_xor(tsum, 16);
        tsum += __shfl_xor(tsum, 32);
        ssum += tsum;
        // NOTE: no barrier here — Ps[w] is wave-local (lgkmcnt orders store->load)

        // PV: O += P x V
        #pragma unroll
        for (int kk = 0; kk < 2; ++kk) {
            const bf8 pa = *(const bf8*)((const char*)Ps[w] + lr * 128 +
                    ((((kk << 2) | lg) ^ (lr & 7)) << 4));
            #pragma unroll
            for (int fn = 0; fn < 4; ++fn) {
                const int rv = fn * 16 + lr;
                const bf8 vf = *(const bf8*)((const char*)Vt[cur] + rv * 128 +
                        ((((kk << 2) | lg) ^ (rv & 7)) << 4));
                o_[fn] = __builtin_amdgcn_mfma_f32_16x16x32_bf16(pa, vf, o_[fn], 0, 0, 0);
            }
        }

        __syncthreads();   // all waves done with buf[cur]; next-tile stage complete
        cur ^= 1;
    }

    const float inv = 1.f / ssum;
    #pragma unroll
    for (int j = 0; j < 4; ++j) {
        const float ij = __shfl(inv, lg * 4 + j);
        const int qr = q0 + w * 16 + lg * 4 + j;
        if (qr <= kmax) {   // live rows only (don't cross into next segment)
            #pragma unroll
            for (int fn = 0; fn < 4; ++fn)
                out[(bb + qr) * DMODEL + hh * 64 + fn * 16 + lr] = f2b(o_[fn][j] * ij);
        }
    }
}

// ---------------- head ----------------

__global__ __launch_bounds__(256) void k_head(
    const float* __restrict__ h, const int* __restrict__ base,
    const float* __restrict__ w1, const float* __restrict__ b1,
    const float* __restrict__ w2, const float* __restrict__ b2,
    float* __restrict__ out)
{
    __shared__ float cbuf[DMODEL];
    __shared__ float p1[DMODEL];
    __shared__ float p2[3];
    const int b = blockIdx.x, tid = threadIdx.x;
    cbuf[tid] = h[(size_t)base[b] * DMODEL + tid];
    __syncthreads();
    float acc = b1[tid];
    #pragma unroll 8
    for (int k = 0; k < DMODEL; ++k) acc = fmaf(cbuf[k], w1[k * DMODEL + tid], acc);
    p1[tid] = fmaxf(acc, 0.f);
    __syncthreads();
    if (tid < 3) {
        float a = b2[tid];
        for (int k = 0; k < DMODEL; ++k) a = fmaf(p1[k], w2[k * 3 + tid], a);
        p2[tid] = a;
    }
    __syncthreads();
    if (tid < 3) {
        float n2 = p2[0]*p2[0] + p2[1]*p2[1] + p2[2]*p2[2];
        out[b * 3 + tid] = p2[tid] * rsqrtf(n2);
    }
}

// ---------------- launch ----------------

extern "C" void kernel_launch(void* const* d_in, const int* in_sizes, int n_in,
                              void* d_out, int out_size, void* d_ws, size_t ws_size,
                              hipStream_t stream) {
    const float* emb   = (const float*)d_in[0];
    const int*   idx   = (const int*)d_in[1];
    const float* projw = (const float*)d_in[4];
    const float* projb = (const float*)d_in[5];
    const float* cls   = (const float*)d_in[6];
    const float* ln1g  = (const float*)d_in[7];
    const float* ln1b  = (const float*)d_in[8];
    const float* qkvw  = (const float*)d_in[9];
    const float* qkvb  = (const float*)d_in[10];
    const float* outw  = (const float*)d_in[11];
    const float* outb  = (const float*)d_in[12];
    const float* ln2g  = (const float*)d_in[13];
    const float* ln2b  = (const float*)d_in[14];
    const float* ff1w  = (const float*)d_in[15];
    const float* ff1b  = (const float*)d_in[16];
    const float* ff2w  = (const float*)d_in[17];
    const float* ff2b  = (const float*)d_in[18];
    const float* h1w   = (const float*)d_in[19];
    const float* h1b   = (const float*)d_in[20];
    const float* h2w   = (const float*)d_in[21];
    const float* h2b   = (const float*)d_in[22];
    float* out = (float*)d_out;

    char* ws = (char*)d_ws;
    int*   counts = (int*)ws;                               // @0
    int*   base   = (int*)(ws + 256);                       // 65 ints
    int*   pos    = (int*)(ws + 1024);                      // NDOM
    int*   rmap   = (int*)(ws + 132096);                    // NDOM
    float* h      = (float*)(ws + 263168);                  // [MC][256] f32
    u16*   ybf    = (u16*)(ws + 34079744);                  // [MC][256] bf16
    u16*   qkvc   = (u16*)(ws + 50988032);                  // [MC][768] bf16
    u16*   ffb    = (u16*)(ws + 101712896);                 // [MC][1024] bf16
    u16*   wq     = (u16*)(ws + 169346048);                 // 4 x [768][256]
    u16*   wo     = (u16*)(ws + 170918912);                 // 4 x [256][256]
    u16*   w1     = (u16*)(ws + 171443200);                 // 4 x [1024][256]
    u16*   w2     = (u16*)(ws + 173540352);                 // 4 x [256][1024]
    u16*   wpj    = (u16*)(ws + 175637504);                 // [256][128]
    u16*   embbf  = qkvc;                                   // alias (pre-loop only)

    k_zero_counts<<<1, 64, 0, stream>>>(counts);
    k_pos<<<NDOM / 256, 256, 0, stream>>>(idx, counts, pos);
    k_base<<<1, 64, 0, stream>>>(counts, base);
    k_rmap<<<NDOM / 256, 256, 0, stream>>>(idx, pos, base, rmap);
    k_b16<<<(NDOM * DIN / 4) / 256, 256, 0, stream>>>(emb, embbf, NDOM * DIN / 4);
    k_wt_all<<<776, 256, 0, stream>>>(projw, qkvw, outw, ff1w, ff2w,
                                      wpj, wq, wo, w1, w2);
    k_init_cls<<<BATCH, 256, 0, stream>>>(base, cls, h);
    k_gemm_bf<0,0,1,0,1><<<dim3(2, 256), 256, 0, stream>>>(
        embbf, wpj, projb, h, nullptr, rmap, DIN, DMODEL);
    k_ln_bf<<<MC / 4, 256, 0, stream>>>(h, ln1g, ln1b, ybf);

    for (int l = 0; l < NLAYER; ++l) {
        // qkv projection
        k_gemm_bf<0,1,0,0,0><<<dim3(6, MTILES), 256, 0, stream>>>(
            ybf, wq + (size_t)l * 196608, qkvb + l * 768, nullptr, qkvc, nullptr, 256, 768);
        // attention
        k_attn_mfma<<<1536, 512, 0, stream>>>(qkvc, counts, base, ybf);
        // out-proj + residual (RMW h), then LN2 -> ybf
        k_gemm_bf<0,0,0,1,0><<<dim3(2, MTILES), 256, 0, stream>>>(
            ybf, wo + (size_t)l * 65536, outb + l * DMODEL, h, nullptr, nullptr, 256, 256);
        k_ln_bf<<<MC / 4, 256, 0, stream>>>(h, ln2g + l * DMODEL, ln2b + l * DMODEL, ybf);
        // ffn
        k_gemm_bf<1,1,0,0,0><<<dim3(8, MTILES), 256, 0, stream>>>(
            ybf, w1 + (size_t)l * 262144, ff1b + l * DFFN, nullptr, ffb, nullptr, 256, 1024);
        k_gemm_bf<0,0,0,1,0><<<dim3(2, MTILES), 256, 0, stream>>>(
            ffb, w2 + (size_t)l * 262144, ff2b + l * DMODEL, h, nullptr, nullptr, 1024, 256);
        if (l < NLAYER - 1)
            k_ln_bf<<<MC / 4, 256, 0, stream>>>(
                h, ln1g + (l + 1) * DMODEL, ln1b + (l + 1) * DMODEL, ybf);
    }

    k_head<<<BATCH, 256, 0, stream>>>(h, base, h1w, h1b, h2w, h2b, out);
}